// Round 1
// baseline (684.354 us; speedup 1.0000x reference)
//
#include <hip/hip_runtime.h>
#include <hip/hip_bf16.h>
#include <math.h>

#define B 4
#define T 512
#define D 256
#define H 8
#define BH (B*H)
#define SCALE 0.0625f

// ---------------- K1: v = x @ wqv_w^T + b, scattered to q/vf/vb [bh][t][w] ----
__global__ __launch_bounds__(256) void k1_qkv(const float* __restrict__ x,
        const float* __restrict__ w, const float* __restrict__ bias,
        float* __restrict__ q, float* __restrict__ vf, float* __restrict__ vb) {
    __shared__ float As[64][33];
    __shared__ float Bs[32][68];
    int bm = blockIdx.x * 64;   // M = B*T = 2048
    int bn = blockIdx.y * 64;   // N = 3*H*D = 6144
    int tid = threadIdx.x;
    int tx = tid & 15, ty = tid >> 4;
    float acc[4][4] = {};
    for (int k0 = 0; k0 < 256; k0 += 32) {
        int r = tid >> 3;
        int c4 = (tid & 7) * 4;
        for (int rr = r; rr < 64; rr += 32) {
            float4 v = *(const float4*)&x[(size_t)(bm + rr) * 256 + k0 + c4];
            As[rr][c4+0]=v.x; As[rr][c4+1]=v.y; As[rr][c4+2]=v.z; As[rr][c4+3]=v.w;
        }
        for (int nn = r; nn < 64; nn += 32) {
            float4 v = *(const float4*)&w[(size_t)(bn + nn) * 256 + k0 + c4];
            Bs[c4+0][nn]=v.x; Bs[c4+1][nn]=v.y; Bs[c4+2][nn]=v.z; Bs[c4+3][nn]=v.w;
        }
        __syncthreads();
        for (int kk = 0; kk < 32; ++kk) {
            float a[4];
            for (int i=0;i<4;++i) a[i] = As[ty*4+i][kk];
            float4 bv = *(const float4*)&Bs[kk][tx*4];
            for (int i=0;i<4;++i) {
                acc[i][0] += a[i]*bv.x; acc[i][1] += a[i]*bv.y;
                acc[i][2] += a[i]*bv.z; acc[i][3] += a[i]*bv.w;
            }
        }
        __syncthreads();
    }
    for (int i=0;i<4;++i) {
        int m = bm + ty*4 + i;
        int b_ = m >> 9, t_ = m & 511;
        for (int j=0;j<4;++j) {
            int n = bn + tx*4 + j;
            float val = acc[i][j] + bias[n];
            int g = n >> 11;
            int rem = n & 2047;
            int h_ = rem >> 8, w_ = rem & 255;
            float* dst = (g==0) ? q : (g==1 ? vf : vb);
            dst[(size_t)((b_*H + h_)*T + t_)*D + w_] = val;
        }
    }
}

// ---------------- K2: a[bh][s][d] = -scale * sum_w |q[s,w] - x[d,w]*wk[h,w]| --
__global__ __launch_bounds__(256) void k2_scores(const float* __restrict__ x,
        const float* __restrict__ wk, const float* __restrict__ q,
        float* __restrict__ a) {
    __shared__ float Qs[64][65];
    __shared__ float Ks[64][65];
    int s0 = blockIdx.x * 64;
    int d0 = blockIdx.y * 64;
    int bh = blockIdx.z;
    int b_ = bh >> 3, h_ = bh & 7;
    int tid = threadIdx.x;
    int tx = tid & 15, ty = tid >> 4;
    const float* qb = q + (size_t)bh * T * D;
    const float* xb = x + (size_t)b_ * T * D;
    float acc[4][4] = {};
    for (int w0 = 0; w0 < 256; w0 += 64) {
        int r = tid >> 4;
        int c4 = (tid & 15) * 4;
        float4 wkv = *(const float4*)&wk[h_*256 + w0 + c4];
        for (int rr = r; rr < 64; rr += 16) {
            float4 v = *(const float4*)&qb[(size_t)(s0+rr)*D + w0 + c4];
            Qs[rr][c4+0]=v.x; Qs[rr][c4+1]=v.y; Qs[rr][c4+2]=v.z; Qs[rr][c4+3]=v.w;
            float4 u = *(const float4*)&xb[(size_t)(d0+rr)*D + w0 + c4];
            Ks[rr][c4+0]=u.x*wkv.x; Ks[rr][c4+1]=u.y*wkv.y;
            Ks[rr][c4+2]=u.z*wkv.z; Ks[rr][c4+3]=u.w*wkv.w;
        }
        __syncthreads();
        for (int ww = 0; ww < 64; ++ww) {
            float qa[4], ka[4];
            for (int i=0;i<4;++i) qa[i] = Qs[ty*4+i][ww];
            for (int j=0;j<4;++j) ka[j] = Ks[tx*4+j][ww];
            for (int i=0;i<4;++i)
                for (int j=0;j<4;++j)
                    acc[i][j] += fabsf(qa[i]-ka[j]);
        }
        __syncthreads();
    }
    float* ab = a + (size_t)bh * T * T;
    for (int i=0;i<4;++i) {
        int s = s0 + ty*4 + i;
        float4 v;
        v.x = -SCALE*acc[i][0]; v.y = -SCALE*acc[i][1];
        v.z = -SCALE*acc[i][2]; v.w = -SCALE*acc[i][3];
        *(float4*)&ab[(size_t)s*T + d0 + tx*4] = v;
    }
}

// ---------------- K3a: per-row (axis2 / keys) max & sumexp ------------------
__global__ __launch_bounds__(256) void k3_rowstats(const float* __restrict__ a,
        float* __restrict__ rmax, float* __restrict__ rsum) {
    int row = blockIdx.x * 4 + (threadIdx.x >> 6);  // [0, BH*T)
    int lane = threadIdx.x & 63;
    const float* ar = a + (size_t)row * T;
    float vals[8];
    float m = -1e30f;
    for (int j = 0; j < 8; ++j) { vals[j] = ar[lane + j*64]; m = fmaxf(m, vals[j]); }
    for (int o = 32; o > 0; o >>= 1) m = fmaxf(m, __shfl_xor(m, o));
    float s = 0.f;
    for (int j = 0; j < 8; ++j) s += expf(vals[j] - m);
    for (int o = 32; o > 0; o >>= 1) s += __shfl_xor(s, o);
    if (lane == 0) { rmax[row] = m; rsum[row] = s; }
}

// ---------------- K3b: per-column (axis1 / queries) max & sumexp ------------
__global__ __launch_bounds__(256) void k3_colstats(const float* __restrict__ a,
        float* __restrict__ cmax, float* __restrict__ csum) {
    int bh = blockIdx.y;
    int d = blockIdx.x * 256 + threadIdx.x;
    const float* ab = a + (size_t)bh * T * T;
    float m = -1e30f;
    for (int s = 0; s < T; ++s) m = fmaxf(m, ab[(size_t)s*T + d]);
    float sum = 0.f;
    for (int s = 0; s < T; ++s) sum += expf(ab[(size_t)s*T + d] - m);
    cmax[bh*T + d] = m;
    csum[bh*T + d] = sum;
}

// ---------------- K4: part[bh][d][w] = af^T·vf + ab·vb ----------------------
__global__ __launch_bounds__(256) void k4_attn(const float* __restrict__ a,
        const float* __restrict__ vf, const float* __restrict__ vb,
        const float* __restrict__ cmax, const float* __restrict__ csum,
        const float* __restrict__ rmax, const float* __restrict__ rsum,
        float* __restrict__ part) {
    __shared__ float P1[32][65];
    __shared__ float P2[64][33];
    __shared__ float Vf[32][68];
    __shared__ float Vb[32][68];
    int d0 = blockIdx.x * 64;
    int w0 = blockIdx.y * 64;
    int bh = blockIdx.z;
    int tid = threadIdx.x;
    int tx = tid & 15, ty = tid >> 4;
    const float* ab = a + (size_t)bh * T * T;
    const float* vfb = vf + (size_t)bh * T * D;
    const float* vbb = vb + (size_t)bh * T * D;
    float acc1[4][4] = {}, acc2[4][4] = {};
    for (int s0 = 0; s0 < T; s0 += 32) {
        {   // P1[ss][dd] = exp(a[s0+ss][d0+dd] - cmax[d0+dd])
            int ss = tid >> 4;
            int c4 = (tid & 15) * 4;
            float4 cm = *(const float4*)&cmax[bh*T + d0 + c4];
            for (int s = ss; s < 32; s += 16) {
                float4 v = *(const float4*)&ab[(size_t)(s0+s)*T + d0 + c4];
                P1[s][c4+0] = expf(v.x - cm.x);
                P1[s][c4+1] = expf(v.y - cm.y);
                P1[s][c4+2] = expf(v.z - cm.z);
                P1[s][c4+3] = expf(v.w - cm.w);
            }
        }
        {   // P2[dd][ss] = exp(a[d0+dd][s0+ss] - rmax[d0+dd])
            int dd = tid >> 3;
            int s4 = (tid & 7) * 4;
            for (int dr = dd; dr < 64; dr += 32) {
                float rm = rmax[bh*T + d0 + dr];
                float4 v = *(const float4*)&ab[(size_t)(d0+dr)*T + s0 + s4];
                P2[dr][s4+0] = expf(v.x - rm);
                P2[dr][s4+1] = expf(v.y - rm);
                P2[dr][s4+2] = expf(v.z - rm);
                P2[dr][s4+3] = expf(v.w - rm);
            }
        }
        {   // Vf/Vb tiles
            int ss = tid >> 4;
            int c4 = (tid & 15) * 4;
            for (int s = ss; s < 32; s += 16) {
                *(float4*)&Vf[s][c4] = *(const float4*)&vfb[(size_t)(s0+s)*D + w0 + c4];
                *(float4*)&Vb[s][c4] = *(const float4*)&vbb[(size_t)(s0+s)*D + w0 + c4];
            }
        }
        __syncthreads();
        for (int ss = 0; ss < 32; ++ss) {
            float4 fv = *(const float4*)&Vf[ss][tx*4];
            float4 bv = *(const float4*)&Vb[ss][tx*4];
            float p1[4], p2[4];
            for (int i=0;i<4;++i) p1[i] = P1[ss][ty*4+i];
            for (int i=0;i<4;++i) p2[i] = P2[ty*4+i][ss];
            for (int i=0;i<4;++i) {
                acc1[i][0] += p1[i]*fv.x; acc1[i][1] += p1[i]*fv.y;
                acc1[i][2] += p1[i]*fv.z; acc1[i][3] += p1[i]*fv.w;
                acc2[i][0] += p2[i]*bv.x; acc2[i][1] += p2[i]*bv.y;
                acc2[i][2] += p2[i]*bv.z; acc2[i][3] += p2[i]*bv.w;
            }
        }
        __syncthreads();
    }
    float* pb = part + (size_t)bh * T * D;
    for (int i=0;i<4;++i) {
        int d = d0 + ty*4 + i;
        float ic = 1.f / csum[bh*T + d];
        float ir = 1.f / rsum[bh*T + d];
        float4 v;
        v.x = acc1[i][0]*ic + acc2[i][0]*ir;
        v.y = acc1[i][1]*ic + acc2[i][1]*ir;
        v.z = acc1[i][2]*ic + acc2[i][2]*ir;
        v.w = acc1[i][3]*ic + acc2[i][3]*ir;
        *(float4*)&pb[(size_t)d*D + w0 + tx*4] = v;
    }
}

// ---------------- K4b: head-reduce + SiLU -----------------------------------
__global__ __launch_bounds__(256) void k4b_reduce_silu(const float* __restrict__ part,
        float* __restrict__ z) {
    int idx = blockIdx.x * 256 + threadIdx.x;   // over B*T*D
    int b_ = idx >> 17;
    int td = idx & 131071;
    float s = 0.f;
    for (int h = 0; h < H; ++h)
        s += part[(size_t)(b_*H + h) * T * D + td];
    z[idx] = s / (1.f + expf(-1.702f * s));
}

// ---------------- K5: out = x + z @ fanin_w^T + fanin_b ---------------------
__global__ __launch_bounds__(256) void k5_fanin(const float* __restrict__ z,
        const float* __restrict__ fw, const float* __restrict__ fb,
        const float* __restrict__ x, float* __restrict__ out) {
    __shared__ float As[64][33];
    __shared__ float Bs[32][68];
    int bm = blockIdx.x * 64;
    int bn = blockIdx.y * 64;
    int tid = threadIdx.x;
    int tx = tid & 15, ty = tid >> 4;
    float acc[4][4] = {};
    for (int k0 = 0; k0 < 256; k0 += 32) {
        int r = tid >> 3, c4 = (tid & 7) * 4;
        for (int rr = r; rr < 64; rr += 32) {
            float4 v = *(const float4*)&z[(size_t)(bm + rr) * 256 + k0 + c4];
            As[rr][c4+0]=v.x; As[rr][c4+1]=v.y; As[rr][c4+2]=v.z; As[rr][c4+3]=v.w;
        }
        for (int nn = r; nn < 64; nn += 32) {
            float4 v = *(const float4*)&fw[(size_t)(bn + nn) * 256 + k0 + c4];
            Bs[c4+0][nn]=v.x; Bs[c4+1][nn]=v.y; Bs[c4+2][nn]=v.z; Bs[c4+3][nn]=v.w;
        }
        __syncthreads();
        for (int kk = 0; kk < 32; ++kk) {
            float a[4];
            for (int i=0;i<4;++i) a[i] = As[ty*4+i][kk];
            float4 bv = *(const float4*)&Bs[kk][tx*4];
            for (int i=0;i<4;++i) {
                acc[i][0] += a[i]*bv.x; acc[i][1] += a[i]*bv.y;
                acc[i][2] += a[i]*bv.z; acc[i][3] += a[i]*bv.w;
            }
        }
        __syncthreads();
    }
    for (int i=0;i<4;++i) {
        int m = bm + ty*4 + i;
        int n = bn + tx*4;
        float4 xv = *(const float4*)&x[(size_t)m*256 + n];
        float4 v;
        v.x = acc[i][0] + fb[n+0] + xv.x;
        v.y = acc[i][1] + fb[n+1] + xv.y;
        v.z = acc[i][2] + fb[n+2] + xv.z;
        v.w = acc[i][3] + fb[n+3] + xv.w;
        *(float4*)&out[(size_t)m*256 + n] = v;
    }
}

extern "C" void kernel_launch(void* const* d_in, const int* in_sizes, int n_in,
                              void* d_out, int out_size, void* d_ws, size_t ws_size,
                              hipStream_t stream) {
    const float* x       = (const float*)d_in[0];
    const float* wk      = (const float*)d_in[1];
    const float* wqv_w   = (const float*)d_in[2];
    const float* wqv_b   = (const float*)d_in[3];
    const float* fanin_w = (const float*)d_in[4];
    const float* fanin_b = (const float*)d_in[5];
    float* ws = (float*)d_ws;
    // workspace layout (floats); part reuses q (dead after k2), z after stats
    float* q    = ws;                      // BHTD = 4194304 (later: part)
    float* vf   = ws + 4194304;            // BHTD
    float* vb   = ws + 8388608;            // BHTD
    float* sc   = ws + 12582912;           // BHTT = 8388608
    float* cmax = ws + 20971520;           // BHT = 16384
    float* csum = ws + 20987904;
    float* rmax = ws + 21004288;
    float* rsum = ws + 21020672;
    float* z    = ws + 21037056;           // BTD = 524288
    float* out  = (float*)d_out;

    k1_qkv        <<<dim3(32, 96), 256, 0, stream>>>(x, wqv_w, wqv_b, q, vf, vb);
    k2_scores     <<<dim3(8, 8, 32), 256, 0, stream>>>(x, wk, q, sc);
    k3_rowstats   <<<dim3(4096), 256, 0, stream>>>(sc, rmax, rsum);
    k3_colstats   <<<dim3(2, 32), 256, 0, stream>>>(sc, cmax, csum);
    k4_attn       <<<dim3(8, 4, 32), 256, 0, stream>>>(sc, vf, vb, cmax, csum, rmax, rsum, q);
    k4b_reduce_silu<<<dim3(2048), 256, 0, stream>>>(q, z);
    k5_fanin      <<<dim3(32, 4), 256, 0, stream>>>(z, fanin_w, fanin_b, x, out);
}

// Round 2
// 275.902 us; speedup vs baseline: 2.4804x; 2.4804x over previous
//
#include <hip/hip_runtime.h>
#include <hip/hip_bf16.h>
#include <math.h>

#define B 4
#define T 512
#define D 256
#define H 8
#define BH (B*H)
#define SCALE 0.0625f

typedef float f32x4 __attribute__((ext_vector_type(4)));
typedef short bf16x8 __attribute__((ext_vector_type(8)));

__device__ __forceinline__ ushort f2b(float f) {
    __hip_bfloat16 h = __float2bfloat16(f);
    return *reinterpret_cast<ushort*>(&h);
}
__device__ __forceinline__ float b2f(ushort u) {
    __hip_bfloat16 h;
    *reinterpret_cast<ushort*>(&h) = u;
    return __bfloat162float(h);
}

// ---- K0: convert x (524288) and wqv_w (1572864) to bf16 --------------------
__global__ __launch_bounds__(256) void k0_convert(const float* __restrict__ x,
        const float* __restrict__ w, ushort* __restrict__ xb, ushort* __restrict__ wb) {
    int i = blockIdx.x * 256 + threadIdx.x;   // quad index, 524288 total
    if (i < 131072) {
        float4 v = ((const float4*)x)[i];
        ((ushort4*)xb)[i] = make_ushort4(f2b(v.x), f2b(v.y), f2b(v.z), f2b(v.w));
    } else {
        int j = i - 131072;
        float4 v = ((const float4*)w)[j];
        ((ushort4*)wb)[j] = make_ushort4(f2b(v.x), f2b(v.y), f2b(v.z), f2b(v.w));
    }
}

// ---- K1: bf16 MFMA GEMM  v = x @ wqv^T + bias -> q [bh][t][w], vfT/vbT [bh][w][t]
__global__ __launch_bounds__(256) void k1_qkv(const ushort* __restrict__ xb,
        const ushort* __restrict__ wb, const float* __restrict__ bias,
        ushort* __restrict__ q, ushort* __restrict__ vf, ushort* __restrict__ vb) {
    __shared__ ushort As[128*40];   // [row m][k] pad 40 for bank spread
    __shared__ ushort Bs[128*40];   // [row n][k]
    int tid = threadIdx.x;
    int lane = tid & 63, wave = tid >> 6;
    int wm = wave >> 1, wn = wave & 1;            // 2x2 wave grid, 64x64 each
    int bm0 = blockIdx.x * 128, bn0 = blockIdx.y * 128;
    f32x4 acc[4][4] = {};
    int sr = tid >> 2, sc = (tid & 3) * 8;
    int fr = lane & 15, fg = (lane >> 4) * 8;
    for (int k0 = 0; k0 < 256; k0 += 32) {
        *(uint4*)&As[sr*40 + sc]      = *(const uint4*)&xb[(size_t)(bm0+sr)*256 + k0 + sc];
        *(uint4*)&As[(sr+64)*40 + sc] = *(const uint4*)&xb[(size_t)(bm0+sr+64)*256 + k0 + sc];
        *(uint4*)&Bs[sr*40 + sc]      = *(const uint4*)&wb[(size_t)(bn0+sr)*256 + k0 + sc];
        *(uint4*)&Bs[(sr+64)*40 + sc] = *(const uint4*)&wb[(size_t)(bn0+sr+64)*256 + k0 + sc];
        __syncthreads();
        bf16x8 af[4], bfv[4];
        #pragma unroll
        for (int i = 0; i < 4; ++i)
            af[i] = *(const bf16x8*)&As[(wm*64 + i*16 + fr)*40 + fg];
        #pragma unroll
        for (int i = 0; i < 4; ++i)
            bfv[i] = *(const bf16x8*)&Bs[(wn*64 + i*16 + fr)*40 + fg];
        #pragma unroll
        for (int mi = 0; mi < 4; ++mi)
            #pragma unroll
            for (int ni = 0; ni < 4; ++ni)
                acc[mi][ni] = __builtin_amdgcn_mfma_f32_16x16x32_bf16(af[mi], bfv[ni], acc[mi][ni], 0, 0, 0);
        __syncthreads();
    }
    int fq = lane >> 4;
    #pragma unroll
    for (int ni = 0; ni < 4; ++ni) {
        int n = bn0 + wn*64 + ni*16 + fr;
        float bn_ = bias[n];
        int g = n >> 11, rem = n & 2047;
        int h_ = rem >> 8, w_ = rem & 255;
        #pragma unroll
        for (int mi = 0; mi < 4; ++mi) {
            int m0 = bm0 + wm*64 + mi*16 + fq*4;
            int b_ = m0 >> 9, t0 = m0 & 511;
            float v0 = acc[mi][ni][0] + bn_;
            float v1 = acc[mi][ni][1] + bn_;
            float v2 = acc[mi][ni][2] + bn_;
            float v3 = acc[mi][ni][3] + bn_;
            if (g == 0) {   // q stays [bh][t][w] for k2
                ushort* dq = q + ((size_t)(b_*H + h_)*T + t0)*D + w_;
                dq[0] = f2b(v0); dq[D] = f2b(v1); dq[2*D] = f2b(v2); dq[3*D] = f2b(v3);
            } else {        // vf/vb transposed [bh][w][t] so k4 B-operand is K-contiguous
                ushort* dv = (g == 1 ? vf : vb) + ((size_t)(b_*H + h_)*D + w_)*T + t0;
                *(ushort4*)dv = make_ushort4(f2b(v0), f2b(v1), f2b(v2), f2b(v3));
            }
        }
    }
}

// ---- K2: E[bh][s][d] = exp(-scale * sum_w |q[s,w] - x[d,w]*wk[h,w]|), + E^T
// scores bounded in [-1.5, 0] => exp without max subtraction is safe.
__global__ __launch_bounds__(256) void k2_scores(const float* __restrict__ x,
        const float* __restrict__ wk, const ushort* __restrict__ q,
        ushort* __restrict__ E, ushort* __restrict__ Et) {
    __shared__ float Qs[64*68];   // [w (reduction)][s], stride 68 => 16B aligned rows, 2-way banks
    __shared__ float Ks[64*68];   // [w][d]
    int s0 = blockIdx.x * 64, d0 = blockIdx.y * 64, bh = blockIdx.z;
    int b_ = bh >> 3, h_ = bh & 7;
    int tid = threadIdx.x;
    int tx = tid & 15, ty = tid >> 4;
    const ushort* qbb = q + (size_t)bh * T * D;
    const float* xbb = x + (size_t)b_ * T * D;
    float acc[4][4] = {};
    int lrow = tid & 63;
    int qseg = (tid >> 6) * 8;
    int kq = tid >> 6;
    for (int w0 = 0; w0 < D; w0 += 64) {
        #pragma unroll
        for (int p = 0; p < 2; ++p) {   // Q tile: bf16 -> f32, transposed into [w][s]
            int c = qseg + p*32;
            uint4 u = *(const uint4*)&qbb[(size_t)(s0+lrow)*D + w0 + c];
            const ushort* up = (const ushort*)&u;
            #pragma unroll
            for (int j = 0; j < 8; ++j)
                Qs[(c+j)*68 + lrow] = b2f(up[j]);
        }
        #pragma unroll
        for (int p = 0; p < 4; ++p) {   // K tile: x*wk, transposed into [w][d]
            int c = (kq + p*4)*4;
            float4 v = *(const float4*)&xbb[(size_t)(d0+lrow)*D + w0 + c];
            float4 wv = *(const float4*)&wk[h_*D + w0 + c];
            Ks[(c+0)*68 + lrow] = v.x*wv.x;
            Ks[(c+1)*68 + lrow] = v.y*wv.y;
            Ks[(c+2)*68 + lrow] = v.z*wv.z;
            Ks[(c+3)*68 + lrow] = v.w*wv.w;
        }
        __syncthreads();
        #pragma unroll 4
        for (int u = 0; u < 64; ++u) {
            f32x4 qa = *(const f32x4*)&Qs[u*68 + ty*4];
            f32x4 ka = *(const f32x4*)&Ks[u*68 + tx*4];
            #pragma unroll
            for (int i = 0; i < 4; ++i)
                #pragma unroll
                for (int j = 0; j < 4; ++j)
                    acc[i][j] += fabsf(qa[i] - ka[j]);
        }
        __syncthreads();
    }
    float e[4][4];
    #pragma unroll
    for (int i = 0; i < 4; ++i)
        #pragma unroll
        for (int j = 0; j < 4; ++j)
            e[i][j] = __expf(-SCALE * acc[i][j]);
    #pragma unroll
    for (int i = 0; i < 4; ++i) {
        *(ushort4*)&E[((size_t)bh*T + s0 + ty*4 + i)*T + d0 + tx*4] =
            make_ushort4(f2b(e[i][0]), f2b(e[i][1]), f2b(e[i][2]), f2b(e[i][3]));
    }
    #pragma unroll
    for (int j = 0; j < 4; ++j) {
        *(ushort4*)&Et[((size_t)bh*T + d0 + tx*4 + j)*T + s0 + ty*4] =
            make_ushort4(f2b(e[0][j]), f2b(e[1][j]), f2b(e[2][j]), f2b(e[3][j]));
    }
}

// ---- K3: rsum[bh][s] = sum_d E ; csum[bh][d] = sum_s E (rows of Et) --------
__global__ __launch_bounds__(256) void k3_sums(const ushort* __restrict__ E,
        const ushort* __restrict__ Et, float* __restrict__ rsum, float* __restrict__ csum) {
    int row = blockIdx.x * 4 + (threadIdx.x >> 6);   // 0..32767
    int lane = threadIdx.x & 63;
    const ushort* src; float* dst;
    if (row < BH*T) { src = E + (size_t)row*T; dst = rsum + row; }
    else            { src = Et + (size_t)(row - BH*T)*T; dst = csum + (row - BH*T); }
    uint4 u = *(const uint4*)&src[lane*8];
    const ushort* up = (const ushort*)&u;
    float s = 0.f;
    #pragma unroll
    for (int j = 0; j < 8; ++j) s += b2f(up[j]);
    #pragma unroll
    for (int o = 32; o > 0; o >>= 1) s += __shfl_xor(s, o);
    if (lane == 0) *dst = s;
}

// ---- K4: dual bf16 MFMA GEMM: part[bh][d][w] = (Et.Vf)/csum[d] + (E.Vb)/rsum[d]
__global__ __launch_bounds__(256) void k4_attn(const ushort* __restrict__ E,
        const ushort* __restrict__ Et, const ushort* __restrict__ vfT,
        const ushort* __restrict__ vbT, const float* __restrict__ rsum,
        const float* __restrict__ csum, float* __restrict__ part) {
    __shared__ ushort A1[128*40];
    __shared__ ushort A2[128*40];
    __shared__ ushort Bf[64*40];
    __shared__ ushort Bb[64*40];
    int d0 = blockIdx.x * 128, w0 = blockIdx.y * 64, bh = blockIdx.z;
    const ushort* Ebb = E  + (size_t)bh*T*T;
    const ushort* Etb = Et + (size_t)bh*T*T;
    const ushort* vfb = vfT + (size_t)bh*D*T;
    const ushort* vbb = vbT + (size_t)bh*D*T;
    int tid = threadIdx.x, lane = tid & 63, wave = tid >> 6;
    int wm = wave >> 1, wn = wave & 1;            // waves: 2 (d) x 2 (w)
    int sr = tid >> 2, sc = (tid & 3) * 8;
    int fr = lane & 15, fg = (lane >> 4) * 8;
    f32x4 acc1[4][2] = {}, acc2[4][2] = {};
    for (int s0 = 0; s0 < T; s0 += 32) {
        *(uint4*)&A1[sr*40 + sc]      = *(const uint4*)&Etb[(size_t)(d0+sr)*T + s0 + sc];
        *(uint4*)&A1[(sr+64)*40 + sc] = *(const uint4*)&Etb[(size_t)(d0+sr+64)*T + s0 + sc];
        *(uint4*)&A2[sr*40 + sc]      = *(const uint4*)&Ebb[(size_t)(d0+sr)*T + s0 + sc];
        *(uint4*)&A2[(sr+64)*40 + sc] = *(const uint4*)&Ebb[(size_t)(d0+sr+64)*T + s0 + sc];
        *(uint4*)&Bf[sr*40 + sc]      = *(const uint4*)&vfb[(size_t)(w0+sr)*T + s0 + sc];
        *(uint4*)&Bb[sr*40 + sc]      = *(const uint4*)&vbb[(size_t)(w0+sr)*T + s0 + sc];
        __syncthreads();
        bf16x8 a1[4], a2[4], bfv[2], bbv[2];
        #pragma unroll
        for (int i = 0; i < 4; ++i) {
            a1[i] = *(const bf16x8*)&A1[(wm*64 + i*16 + fr)*40 + fg];
            a2[i] = *(const bf16x8*)&A2[(wm*64 + i*16 + fr)*40 + fg];
        }
        #pragma unroll
        for (int i = 0; i < 2; ++i) {
            bfv[i] = *(const bf16x8*)&Bf[(wn*32 + i*16 + fr)*40 + fg];
            bbv[i] = *(const bf16x8*)&Bb[(wn*32 + i*16 + fr)*40 + fg];
        }
        #pragma unroll
        for (int mi = 0; mi < 4; ++mi)
            #pragma unroll
            for (int ni = 0; ni < 2; ++ni) {
                acc1[mi][ni] = __builtin_amdgcn_mfma_f32_16x16x32_bf16(a1[mi], bfv[ni], acc1[mi][ni], 0, 0, 0);
                acc2[mi][ni] = __builtin_amdgcn_mfma_f32_16x16x32_bf16(a2[mi], bbv[ni], acc2[mi][ni], 0, 0, 0);
            }
        __syncthreads();
    }
    int fq = lane >> 4;
    float* pb = part + (size_t)bh*T*D;
    #pragma unroll
    for (int mi = 0; mi < 4; ++mi)
        #pragma unroll
        for (int r = 0; r < 4; ++r) {
            int d = d0 + wm*64 + mi*16 + fq*4 + r;
            float ic = 1.f / csum[bh*T + d];
            float ir = 1.f / rsum[bh*T + d];
            #pragma unroll
            for (int ni = 0; ni < 2; ++ni) {
                int w = w0 + wn*32 + ni*16 + fr;
                pb[(size_t)d*D + w] = acc1[mi][ni][r]*ic + acc2[mi][ni][r]*ir;
            }
        }
}

// ---- K4b: head-reduce + SiLU ----------------------------------------------
__global__ __launch_bounds__(256) void k4b_reduce_silu(const float* __restrict__ part,
        float* __restrict__ z) {
    int idx = blockIdx.x * 256 + threadIdx.x;   // over B*T*D
    int b_ = idx >> 17;
    int td = idx & 131071;
    float s = 0.f;
    #pragma unroll
    for (int h = 0; h < H; ++h)
        s += part[(size_t)(b_*H + h) * T * D + td];
    z[idx] = s / (1.f + __expf(-1.702f * s));
}

// ---- K5: out = x + z @ fanin_w^T + fanin_b (fp32, small) -------------------
__global__ __launch_bounds__(256) void k5_fanin(const float* __restrict__ z,
        const float* __restrict__ fw, const float* __restrict__ fb,
        const float* __restrict__ x, float* __restrict__ out) {
    __shared__ float As[64][33];
    __shared__ float Bs[32][68];
    int bm = blockIdx.x * 64;
    int bn = blockIdx.y * 64;
    int tid = threadIdx.x;
    int tx = tid & 15, ty = tid >> 4;
    float acc[4][4] = {};
    for (int k0 = 0; k0 < 256; k0 += 32) {
        int r = tid >> 3, c4 = (tid & 7) * 4;
        for (int rr = r; rr < 64; rr += 32) {
            float4 v = *(const float4*)&z[(size_t)(bm + rr) * 256 + k0 + c4];
            As[rr][c4+0]=v.x; As[rr][c4+1]=v.y; As[rr][c4+2]=v.z; As[rr][c4+3]=v.w;
        }
        for (int nn = r; nn < 64; nn += 32) {
            float4 v = *(const float4*)&fw[(size_t)(bn + nn) * 256 + k0 + c4];
            Bs[c4+0][nn]=v.x; Bs[c4+1][nn]=v.y; Bs[c4+2][nn]=v.z; Bs[c4+3][nn]=v.w;
        }
        __syncthreads();
        for (int kk = 0; kk < 32; ++kk) {
            float a[4];
            #pragma unroll
            for (int i=0;i<4;++i) a[i] = As[ty*4+i][kk];
            float4 bv = *(const float4*)&Bs[kk][tx*4];
            #pragma unroll
            for (int i=0;i<4;++i) {
                acc[i][0] += a[i]*bv.x; acc[i][1] += a[i]*bv.y;
                acc[i][2] += a[i]*bv.z; acc[i][3] += a[i]*bv.w;
            }
        }
        __syncthreads();
    }
    #pragma unroll
    for (int i=0;i<4;++i) {
        int m = bm + ty*4 + i;
        int n = bn + tx*4;
        float4 xv = *(const float4*)&x[(size_t)m*256 + n];
        float4 v;
        v.x = acc[i][0] + fb[n+0] + xv.x;
        v.y = acc[i][1] + fb[n+1] + xv.y;
        v.z = acc[i][2] + fb[n+2] + xv.z;
        v.w = acc[i][3] + fb[n+3] + xv.w;
        *(float4*)&out[(size_t)m*256 + n] = v;
    }
}

extern "C" void kernel_launch(void* const* d_in, const int* in_sizes, int n_in,
                              void* d_out, int out_size, void* d_ws, size_t ws_size,
                              hipStream_t stream) {
    const float* x       = (const float*)d_in[0];
    const float* wk      = (const float*)d_in[1];
    const float* wqv_w   = (const float*)d_in[2];
    const float* wqv_b   = (const float*)d_in[3];
    const float* fanin_w = (const float*)d_in[4];
    const float* fanin_b = (const float*)d_in[5];
    char* wsb = (char*)d_ws;
    ushort* xb   = (ushort*)(wsb);                 // 1,048,576 B
    ushort* wqvb = (ushort*)(wsb + 1048576);       // 3,145,728
    ushort* qb   = (ushort*)(wsb + 4194304);       // 8,388,608  [bh][t][w]
    ushort* vfT  = (ushort*)(wsb + 12582912);      // 8,388,608  [bh][w][t]
    ushort* vbT  = (ushort*)(wsb + 20971520);      // 8,388,608
    ushort* Eb   = (ushort*)(wsb + 29360128);      // 16,777,216 [bh][s][d]
    ushort* Etb  = (ushort*)(wsb + 46137344);      // 16,777,216 [bh][d][s]
    float*  rsum = (float*)(wsb + 62914560);       // 65,536
    float*  csum = (float*)(wsb + 62980096);       // 65,536
    float*  part = (float*)(wsb + 63045632);       // 16,777,216
    float*  z    = (float*)(wsb + 79822848);       // 2,097,152 -> end 81,920,000
    float* out   = (float*)d_out;

    k0_convert     <<<2048, 256, 0, stream>>>(x, wqv_w, xb, wqvb);
    k1_qkv         <<<dim3(16, 48), 256, 0, stream>>>(xb, wqvb, wqv_b, qb, vfT, vbT);
    k2_scores      <<<dim3(8, 8, 32), 256, 0, stream>>>(x, wk, qb, Eb, Etb);
    k3_sums        <<<8192, 256, 0, stream>>>(Eb, Etb, rsum, csum);
    k4_attn        <<<dim3(4, 4, 32), 256, 0, stream>>>(Eb, Etb, vfT, vbT, rsum, csum, part);
    k4b_reduce_silu<<<2048, 256, 0, stream>>>(part, z);
    k5_fanin       <<<dim3(32, 4), 256, 0, stream>>>(z, fanin_w, fanin_b, x, out);
}

// Round 3
// 258.770 us; speedup vs baseline: 2.6446x; 1.0662x over previous
//
#include <hip/hip_runtime.h>
#include <hip/hip_bf16.h>
#include <math.h>

#define B 4
#define T 512
#define D 256
#define H 8
#define BH (B*H)
#define SCALE 0.0625f

typedef float f32x4 __attribute__((ext_vector_type(4)));
typedef short bf16x8 __attribute__((ext_vector_type(8)));
typedef _Float16 f16x2 __attribute__((ext_vector_type(2)));
typedef unsigned int u32x4 __attribute__((ext_vector_type(4)));

__device__ __forceinline__ ushort f2b(float f) {
    __hip_bfloat16 h = __float2bfloat16(f);
    return *reinterpret_cast<ushort*>(&h);
}
__device__ __forceinline__ float b2f(ushort u) {
    __hip_bfloat16 h;
    *reinterpret_cast<ushort*>(&h) = u;
    return __bfloat162float(h);
}

// ---- K0: convert x (524288) and wqv_w (1572864) to bf16 --------------------
__global__ __launch_bounds__(256) void k0_convert(const float* __restrict__ x,
        const float* __restrict__ w, ushort* __restrict__ xb, ushort* __restrict__ wb) {
    int i = blockIdx.x * 256 + threadIdx.x;   // quad index, 524288 total
    if (i < 131072) {
        float4 v = ((const float4*)x)[i];
        ((ushort4*)xb)[i] = make_ushort4(f2b(v.x), f2b(v.y), f2b(v.z), f2b(v.w));
    } else {
        int j = i - 131072;
        float4 v = ((const float4*)w)[j];
        ((ushort4*)wb)[j] = make_ushort4(f2b(v.x), f2b(v.y), f2b(v.z), f2b(v.w));
    }
}

// ---- K1: bf16 MFMA GEMM  v = x @ wqv^T + bias -> q [bh][t][w], vfT/vbT [bh][w][t]
__global__ __launch_bounds__(256) void k1_qkv(const ushort* __restrict__ xb,
        const ushort* __restrict__ wb, const float* __restrict__ bias,
        ushort* __restrict__ q, ushort* __restrict__ vf, ushort* __restrict__ vb) {
    __shared__ ushort As[128*40];   // [row m][k] pad 40 for bank spread
    __shared__ ushort Bs[128*40];   // [row n][k]
    int tid = threadIdx.x;
    int lane = tid & 63, wave = tid >> 6;
    int wm = wave >> 1, wn = wave & 1;            // 2x2 wave grid, 64x64 each
    int bm0 = blockIdx.x * 128, bn0 = blockIdx.y * 128;
    f32x4 acc[4][4] = {};
    int sr = tid >> 2, sc = (tid & 3) * 8;
    int fr = lane & 15, fg = (lane >> 4) * 8;
    for (int k0 = 0; k0 < 256; k0 += 32) {
        *(uint4*)&As[sr*40 + sc]      = *(const uint4*)&xb[(size_t)(bm0+sr)*256 + k0 + sc];
        *(uint4*)&As[(sr+64)*40 + sc] = *(const uint4*)&xb[(size_t)(bm0+sr+64)*256 + k0 + sc];
        *(uint4*)&Bs[sr*40 + sc]      = *(const uint4*)&wb[(size_t)(bn0+sr)*256 + k0 + sc];
        *(uint4*)&Bs[(sr+64)*40 + sc] = *(const uint4*)&wb[(size_t)(bn0+sr+64)*256 + k0 + sc];
        __syncthreads();
        bf16x8 af[4], bfv[4];
        #pragma unroll
        for (int i = 0; i < 4; ++i)
            af[i] = *(const bf16x8*)&As[(wm*64 + i*16 + fr)*40 + fg];
        #pragma unroll
        for (int i = 0; i < 4; ++i)
            bfv[i] = *(const bf16x8*)&Bs[(wn*64 + i*16 + fr)*40 + fg];
        #pragma unroll
        for (int mi = 0; mi < 4; ++mi)
            #pragma unroll
            for (int ni = 0; ni < 4; ++ni)
                acc[mi][ni] = __builtin_amdgcn_mfma_f32_16x16x32_bf16(af[mi], bfv[ni], acc[mi][ni], 0, 0, 0);
        __syncthreads();
    }
    int fq = lane >> 4;
    #pragma unroll
    for (int ni = 0; ni < 4; ++ni) {
        int n = bn0 + wn*64 + ni*16 + fr;
        float bn_ = bias[n];
        int g = n >> 11, rem = n & 2047;
        int h_ = rem >> 8, w_ = rem & 255;
        #pragma unroll
        for (int mi = 0; mi < 4; ++mi) {
            int m0 = bm0 + wm*64 + mi*16 + fq*4;
            int b_ = m0 >> 9, t0 = m0 & 511;
            float v0 = acc[mi][ni][0] + bn_;
            float v1 = acc[mi][ni][1] + bn_;
            float v2 = acc[mi][ni][2] + bn_;
            float v3 = acc[mi][ni][3] + bn_;
            if (g == 0) {   // q stays [bh][t][w] for k2
                ushort* dq = q + ((size_t)(b_*H + h_)*T + t0)*D + w_;
                dq[0] = f2b(v0); dq[D] = f2b(v1); dq[2*D] = f2b(v2); dq[3*D] = f2b(v3);
            } else {        // vf/vb transposed [bh][w][t] so k4 B-operand is K-contiguous
                ushort* dv = (g == 1 ? vf : vb) + ((size_t)(b_*H + h_)*D + w_)*T + t0;
                *(ushort4*)dv = make_ushort4(f2b(v0), f2b(v1), f2b(v2), f2b(v3));
            }
        }
    }
}

// ---- K2: E[bh][s][d] = exp(-scale * sum_w |q[s,w] - x[d,w]*wk[h,w]|), + E^T
// Packed-f16 inner loop: LDS holds half2 pairs interleaved along the reduction
// axis w, so v_pk_add/max_f16 process 2 reduction elements per instruction.
// Partials fold to f32 every 64 w (per chunk); scores bounded in [-1.5, 0].
__global__ __launch_bounds__(256) void k2_scores(const float* __restrict__ x,
        const float* __restrict__ wk, const ushort* __restrict__ q,
        ushort* __restrict__ E, ushort* __restrict__ Et) {
    __shared__ __align__(16) uint Qs[32*68];   // [w-pair up][s], half2 payload
    __shared__ __align__(16) uint Ks[32*68];   // [w-pair up][d]
    int s0 = blockIdx.x * 64, d0 = blockIdx.y * 64, bh = blockIdx.z;
    int b_ = bh >> 3, h_ = bh & 7;
    int tid = threadIdx.x;
    int tx = tid & 15, ty = tid >> 4;
    const ushort* qbb = q + (size_t)bh * T * D;
    const float* xbb = x + (size_t)b_ * T * D;
    int lrow = tid & 63;
    int seg = tid >> 6;           // 0..3
    float accf[4][4] = {};
    for (int w0 = 0; w0 < D; w0 += 64) {
        // ---- stage Q tile (bf16 -> f16 pairs over w) ----
        #pragma unroll
        for (int p = 0; p < 2; ++p) {
            int c = seg*8 + p*32;
            uint4 u = *(const uint4*)&qbb[(size_t)(s0+lrow)*D + w0 + c];
            const ushort* uptr = (const ushort*)&u;
            #pragma unroll
            for (int jj = 0; jj < 4; ++jj) {
                f16x2 t;
                t[0] = (_Float16)b2f(uptr[2*jj]);
                t[1] = (_Float16)b2f(uptr[2*jj+1]);
                Qs[((c>>1)+jj)*68 + lrow] = *(uint*)&t;
            }
        }
        // ---- stage K tile (f32 x*wk -> f16 pairs over w) ----
        #pragma unroll
        for (int p = 0; p < 2; ++p) {
            int c = seg*8 + p*32;
            float4 v0 = *(const float4*)&xbb[(size_t)(d0+lrow)*D + w0 + c];
            float4 v1 = *(const float4*)&xbb[(size_t)(d0+lrow)*D + w0 + c + 4];
            float4 wv0 = *(const float4*)&wk[h_*D + w0 + c];
            float4 wv1 = *(const float4*)&wk[h_*D + w0 + c + 4];
            float kv[8] = {v0.x*wv0.x, v0.y*wv0.y, v0.z*wv0.z, v0.w*wv0.w,
                           v1.x*wv1.x, v1.y*wv1.y, v1.z*wv1.z, v1.w*wv1.w};
            #pragma unroll
            for (int jj = 0; jj < 4; ++jj) {
                f16x2 t;
                t[0] = (_Float16)kv[2*jj];
                t[1] = (_Float16)kv[2*jj+1];
                Ks[((c>>1)+jj)*68 + lrow] = *(uint*)&t;
            }
        }
        __syncthreads();
        // ---- inner: 32 w-pair steps, 16 (i,j) packed abs-diff accumulations --
        uint acc2[4][4] = {};
        #pragma unroll 8
        for (int up = 0; up < 32; ++up) {
            u32x4 qv = *(const u32x4*)&Qs[up*68 + ty*4];
            u32x4 kv = *(const u32x4*)&Ks[up*68 + tx*4];
            #pragma unroll
            for (int i = 0; i < 4; ++i) {
                #pragma unroll
                for (int j = 0; j < 4; ++j) {
                    uint tmp;
                    asm("v_pk_add_f16 %1, %2, %3 neg_lo:[0,1] neg_hi:[0,1]\n\t"
                        "v_pk_max_f16 %1, %1, %1 neg_lo:[0,1] neg_hi:[0,1]\n\t"
                        "v_pk_add_f16 %0, %0, %1"
                        : "+v"(acc2[i][j]), "=&v"(tmp)
                        : "v"(qv[i]), "v"(kv[j]));
                }
            }
        }
        // fold f16 partials (64 w-terms) into f32
        #pragma unroll
        for (int i = 0; i < 4; ++i)
            #pragma unroll
            for (int j = 0; j < 4; ++j) {
                f16x2 t = *(f16x2*)&acc2[i][j];
                accf[i][j] += (float)t[0] + (float)t[1];
            }
        __syncthreads();
    }
    float e[4][4];
    #pragma unroll
    for (int i = 0; i < 4; ++i)
        #pragma unroll
        for (int j = 0; j < 4; ++j)
            e[i][j] = __expf(-SCALE * accf[i][j]);
    #pragma unroll
    for (int i = 0; i < 4; ++i) {
        *(ushort4*)&E[((size_t)bh*T + s0 + ty*4 + i)*T + d0 + tx*4] =
            make_ushort4(f2b(e[i][0]), f2b(e[i][1]), f2b(e[i][2]), f2b(e[i][3]));
    }
    #pragma unroll
    for (int j = 0; j < 4; ++j) {
        *(ushort4*)&Et[((size_t)bh*T + d0 + tx*4 + j)*T + s0 + ty*4] =
            make_ushort4(f2b(e[0][j]), f2b(e[1][j]), f2b(e[2][j]), f2b(e[3][j]));
    }
}

// ---- K3: rsum[bh][s] = sum_d E ; csum[bh][d] = sum_s E (rows of Et) --------
__global__ __launch_bounds__(256) void k3_sums(const ushort* __restrict__ E,
        const ushort* __restrict__ Et, float* __restrict__ rsum, float* __restrict__ csum) {
    int row = blockIdx.x * 4 + (threadIdx.x >> 6);   // 0..32767
    int lane = threadIdx.x & 63;
    const ushort* src; float* dst;
    if (row < BH*T) { src = E + (size_t)row*T; dst = rsum + row; }
    else            { src = Et + (size_t)(row - BH*T)*T; dst = csum + (row - BH*T); }
    uint4 u = *(const uint4*)&src[lane*8];
    const ushort* up = (const ushort*)&u;
    float s = 0.f;
    #pragma unroll
    for (int j = 0; j < 8; ++j) s += b2f(up[j]);
    #pragma unroll
    for (int o = 32; o > 0; o >>= 1) s += __shfl_xor(s, o);
    if (lane == 0) *dst = s;
}

// ---- K4: dual bf16 MFMA GEMM: part[bh][d][w] = (Et.Vf)/csum[d] + (E.Vb)/rsum[d]
__global__ __launch_bounds__(256) void k4_attn(const ushort* __restrict__ E,
        const ushort* __restrict__ Et, const ushort* __restrict__ vfT,
        const ushort* __restrict__ vbT, const float* __restrict__ rsum,
        const float* __restrict__ csum, float* __restrict__ part) {
    __shared__ ushort A1[128*40];
    __shared__ ushort A2[128*40];
    __shared__ ushort Bf[64*40];
    __shared__ ushort Bb[64*40];
    int d0 = blockIdx.x * 128, w0 = blockIdx.y * 64, bh = blockIdx.z;
    const ushort* Ebb = E  + (size_t)bh*T*T;
    const ushort* Etb = Et + (size_t)bh*T*T;
    const ushort* vfb = vfT + (size_t)bh*D*T;
    const ushort* vbb = vbT + (size_t)bh*D*T;
    int tid = threadIdx.x, lane = tid & 63, wave = tid >> 6;
    int wm = wave >> 1, wn = wave & 1;            // waves: 2 (d) x 2 (w)
    int sr = tid >> 2, sc = (tid & 3) * 8;
    int fr = lane & 15, fg = (lane >> 4) * 8;
    f32x4 acc1[4][2] = {}, acc2[4][2] = {};
    for (int s0 = 0; s0 < T; s0 += 32) {
        *(uint4*)&A1[sr*40 + sc]      = *(const uint4*)&Etb[(size_t)(d0+sr)*T + s0 + sc];
        *(uint4*)&A1[(sr+64)*40 + sc] = *(const uint4*)&Etb[(size_t)(d0+sr+64)*T + s0 + sc];
        *(uint4*)&A2[sr*40 + sc]      = *(const uint4*)&Ebb[(size_t)(d0+sr)*T + s0 + sc];
        *(uint4*)&A2[(sr+64)*40 + sc] = *(const uint4*)&Ebb[(size_t)(d0+sr+64)*T + s0 + sc];
        *(uint4*)&Bf[sr*40 + sc]      = *(const uint4*)&vfb[(size_t)(w0+sr)*T + s0 + sc];
        *(uint4*)&Bb[sr*40 + sc]      = *(const uint4*)&vbb[(size_t)(w0+sr)*T + s0 + sc];
        __syncthreads();
        bf16x8 a1[4], a2[4], bfv[2], bbv[2];
        #pragma unroll
        for (int i = 0; i < 4; ++i) {
            a1[i] = *(const bf16x8*)&A1[(wm*64 + i*16 + fr)*40 + fg];
            a2[i] = *(const bf16x8*)&A2[(wm*64 + i*16 + fr)*40 + fg];
        }
        #pragma unroll
        for (int i = 0; i < 2; ++i) {
            bfv[i] = *(const bf16x8*)&Bf[(wn*32 + i*16 + fr)*40 + fg];
            bbv[i] = *(const bf16x8*)&Bb[(wn*32 + i*16 + fr)*40 + fg];
        }
        #pragma unroll
        for (int mi = 0; mi < 4; ++mi)
            #pragma unroll
            for (int ni = 0; ni < 2; ++ni) {
                acc1[mi][ni] = __builtin_amdgcn_mfma_f32_16x16x32_bf16(a1[mi], bfv[ni], acc1[mi][ni], 0, 0, 0);
                acc2[mi][ni] = __builtin_amdgcn_mfma_f32_16x16x32_bf16(a2[mi], bbv[ni], acc2[mi][ni], 0, 0, 0);
            }
        __syncthreads();
    }
    int fq = lane >> 4;
    float* pb = part + (size_t)bh*T*D;
    #pragma unroll
    for (int mi = 0; mi < 4; ++mi)
        #pragma unroll
        for (int r = 0; r < 4; ++r) {
            int d = d0 + wm*64 + mi*16 + fq*4 + r;
            float ic = 1.f / csum[bh*T + d];
            float ir = 1.f / rsum[bh*T + d];
            #pragma unroll
            for (int ni = 0; ni < 2; ++ni) {
                int w = w0 + wn*32 + ni*16 + fr;
                pb[(size_t)d*D + w] = acc1[mi][ni][r]*ic + acc2[mi][ni][r]*ir;
            }
        }
}

// ---- K4b: head-reduce + SiLU ----------------------------------------------
__global__ __launch_bounds__(256) void k4b_reduce_silu(const float* __restrict__ part,
        float* __restrict__ z) {
    int idx = blockIdx.x * 256 + threadIdx.x;   // over B*T*D
    int b_ = idx >> 17;
    int td = idx & 131071;
    float s = 0.f;
    #pragma unroll
    for (int h = 0; h < H; ++h)
        s += part[(size_t)(b_*H + h) * T * D + td];
    z[idx] = s / (1.f + __expf(-1.702f * s));
}

// ---- K5: out = x + z @ fanin_w^T + fanin_b (fp32, small) -------------------
__global__ __launch_bounds__(256) void k5_fanin(const float* __restrict__ z,
        const float* __restrict__ fw, const float* __restrict__ fb,
        const float* __restrict__ x, float* __restrict__ out) {
    __shared__ float As[64][33];
    __shared__ float Bs[32][68];
    int bm = blockIdx.x * 64;
    int bn = blockIdx.y * 64;
    int tid = threadIdx.x;
    int tx = tid & 15, ty = tid >> 4;
    float acc[4][4] = {};
    for (int k0 = 0; k0 < 256; k0 += 32) {
        int r = tid >> 3, c4 = (tid & 7) * 4;
        for (int rr = r; rr < 64; rr += 32) {
            float4 v = *(const float4*)&z[(size_t)(bm + rr) * 256 + k0 + c4];
            As[rr][c4+0]=v.x; As[rr][c4+1]=v.y; As[rr][c4+2]=v.z; As[rr][c4+3]=v.w;
        }
        for (int nn = r; nn < 64; nn += 32) {
            float4 v = *(const float4*)&fw[(size_t)(bn + nn) * 256 + k0 + c4];
            Bs[c4+0][nn]=v.x; Bs[c4+1][nn]=v.y; Bs[c4+2][nn]=v.z; Bs[c4+3][nn]=v.w;
        }
        __syncthreads();
        for (int kk = 0; kk < 32; ++kk) {
            float a[4];
            #pragma unroll
            for (int i=0;i<4;++i) a[i] = As[ty*4+i][kk];
            float4 bv = *(const float4*)&Bs[kk][tx*4];
            #pragma unroll
            for (int i=0;i<4;++i) {
                acc[i][0] += a[i]*bv.x; acc[i][1] += a[i]*bv.y;
                acc[i][2] += a[i]*bv.z; acc[i][3] += a[i]*bv.w;
            }
        }
        __syncthreads();
    }
    #pragma unroll
    for (int i=0;i<4;++i) {
        int m = bm + ty*4 + i;
        int n = bn + tx*4;
        float4 xv = *(const float4*)&x[(size_t)m*256 + n];
        float4 v;
        v.x = acc[i][0] + fb[n+0] + xv.x;
        v.y = acc[i][1] + fb[n+1] + xv.y;
        v.z = acc[i][2] + fb[n+2] + xv.z;
        v.w = acc[i][3] + fb[n+3] + xv.w;
        *(float4*)&out[(size_t)m*256 + n] = v;
    }
}

extern "C" void kernel_launch(void* const* d_in, const int* in_sizes, int n_in,
                              void* d_out, int out_size, void* d_ws, size_t ws_size,
                              hipStream_t stream) {
    const float* x       = (const float*)d_in[0];
    const float* wk      = (const float*)d_in[1];
    const float* wqv_w   = (const float*)d_in[2];
    const float* wqv_b   = (const float*)d_in[3];
    const float* fanin_w = (const float*)d_in[4];
    const float* fanin_b = (const float*)d_in[5];
    char* wsb = (char*)d_ws;
    ushort* xb   = (ushort*)(wsb);                 // 1,048,576 B
    ushort* wqvb = (ushort*)(wsb + 1048576);       // 3,145,728
    ushort* qb   = (ushort*)(wsb + 4194304);       // 8,388,608  [bh][t][w]
    ushort* vfT  = (ushort*)(wsb + 12582912);      // 8,388,608  [bh][w][t]
    ushort* vbT  = (ushort*)(wsb + 20971520);      // 8,388,608
    ushort* Eb   = (ushort*)(wsb + 29360128);      // 16,777,216 [bh][s][d]
    ushort* Etb  = (ushort*)(wsb + 46137344);      // 16,777,216 [bh][d][s]
    float*  rsum = (float*)(wsb + 62914560);       // 65,536
    float*  csum = (float*)(wsb + 62980096);       // 65,536
    float*  part = (float*)(wsb + 63045632);       // 16,777,216
    float*  z    = (float*)(wsb + 79822848);       // 2,097,152 -> end 81,920,000
    float* out   = (float*)d_out;

    k0_convert     <<<2048, 256, 0, stream>>>(x, wqv_w, xb, wqvb);
    k1_qkv         <<<dim3(16, 48), 256, 0, stream>>>(xb, wqvb, wqv_b, qb, vfT, vbT);
    k2_scores      <<<dim3(8, 8, 32), 256, 0, stream>>>(x, wk, qb, Eb, Etb);
    k3_sums        <<<8192, 256, 0, stream>>>(Eb, Etb, rsum, csum);
    k4_attn        <<<dim3(4, 4, 32), 256, 0, stream>>>(Eb, Etb, vfT, vbT, rsum, csum, part);
    k4b_reduce_silu<<<2048, 256, 0, stream>>>(part, z);
    k5_fanin       <<<dim3(32, 4), 256, 0, stream>>>(z, fanin_w, fanin_b, x, out);
}

// Round 4
// 238.535 us; speedup vs baseline: 2.8690x; 1.0848x over previous
//
#include <hip/hip_runtime.h>
#include <hip/hip_bf16.h>
#include <math.h>

#define B 4
#define T 512
#define D 256
#define H 8
#define BH (B*H)
#define SCALE 0.0625f

typedef float f32x4 __attribute__((ext_vector_type(4)));
typedef short bf16x8 __attribute__((ext_vector_type(8)));
typedef _Float16 f16x2 __attribute__((ext_vector_type(2)));
typedef unsigned int u32x4 __attribute__((ext_vector_type(4)));

__device__ __forceinline__ ushort f2b(float f) {
    __hip_bfloat16 h = __float2bfloat16(f);
    return *reinterpret_cast<ushort*>(&h);
}
__device__ __forceinline__ float b2f(ushort u) {
    __hip_bfloat16 h;
    *reinterpret_cast<ushort*>(&h) = u;
    return __bfloat162float(h);
}
__device__ __forceinline__ ushort f2h(float f) {
    _Float16 h = (_Float16)f;
    ushort u; __builtin_memcpy(&u, &h, 2); return u;
}
__device__ __forceinline__ float h2f(ushort u) {
    _Float16 h; __builtin_memcpy(&h, &u, 2); return (float)h;
}

// ---- K0: x -> bf16 (for k1 MFMA) + f16 (for k2); wqv_w -> bf16; wk -> f16 --
__global__ __launch_bounds__(256) void k0_convert(const float* __restrict__ x,
        const float* __restrict__ w, const float* __restrict__ wk,
        ushort* __restrict__ xb, ushort* __restrict__ xh,
        ushort* __restrict__ wb, ushort* __restrict__ wkh) {
    int i = blockIdx.x * 256 + threadIdx.x;
    if (i < 131072) {
        float4 v = ((const float4*)x)[i];
        ((ushort4*)xb)[i] = make_ushort4(f2b(v.x), f2b(v.y), f2b(v.z), f2b(v.w));
        ((ushort4*)xh)[i] = make_ushort4(f2h(v.x), f2h(v.y), f2h(v.z), f2h(v.w));
    } else if (i < 524288) {
        int j = i - 131072;
        float4 v = ((const float4*)w)[j];
        ((ushort4*)wb)[j] = make_ushort4(f2b(v.x), f2b(v.y), f2b(v.z), f2b(v.w));
    } else if (i < 524288 + 512) {
        int j = i - 524288;
        float4 v = ((const float4*)wk)[j];
        ((ushort4*)wkh)[j] = make_ushort4(f2h(v.x), f2h(v.y), f2h(v.z), f2h(v.w));
    }
}

// ---- K1: bf16 MFMA GEMM  v = x @ wqv^T + bias -> q(f16) [bh][t][w], vfT/vbT(bf16) [bh][w][t]
__global__ __launch_bounds__(256) void k1_qkv(const ushort* __restrict__ xb,
        const ushort* __restrict__ wb, const float* __restrict__ bias,
        ushort* __restrict__ q, ushort* __restrict__ vf, ushort* __restrict__ vb) {
    __shared__ ushort As[128*40];
    __shared__ ushort Bs[128*40];
    int tid = threadIdx.x;
    int lane = tid & 63, wave = tid >> 6;
    int wm = wave >> 1, wn = wave & 1;
    int bm0 = blockIdx.x * 128, bn0 = blockIdx.y * 128;
    f32x4 acc[4][4] = {};
    int sr = tid >> 2, sc = (tid & 3) * 8;
    int fr = lane & 15, fg = (lane >> 4) * 8;
    for (int k0 = 0; k0 < 256; k0 += 32) {
        *(uint4*)&As[sr*40 + sc]      = *(const uint4*)&xb[(size_t)(bm0+sr)*256 + k0 + sc];
        *(uint4*)&As[(sr+64)*40 + sc] = *(const uint4*)&xb[(size_t)(bm0+sr+64)*256 + k0 + sc];
        *(uint4*)&Bs[sr*40 + sc]      = *(const uint4*)&wb[(size_t)(bn0+sr)*256 + k0 + sc];
        *(uint4*)&Bs[(sr+64)*40 + sc] = *(const uint4*)&wb[(size_t)(bn0+sr+64)*256 + k0 + sc];
        __syncthreads();
        bf16x8 af[4], bfv[4];
        #pragma unroll
        for (int i = 0; i < 4; ++i)
            af[i] = *(const bf16x8*)&As[(wm*64 + i*16 + fr)*40 + fg];
        #pragma unroll
        for (int i = 0; i < 4; ++i)
            bfv[i] = *(const bf16x8*)&Bs[(wn*64 + i*16 + fr)*40 + fg];
        #pragma unroll
        for (int mi = 0; mi < 4; ++mi)
            #pragma unroll
            for (int ni = 0; ni < 4; ++ni)
                acc[mi][ni] = __builtin_amdgcn_mfma_f32_16x16x32_bf16(af[mi], bfv[ni], acc[mi][ni], 0, 0, 0);
        __syncthreads();
    }
    int fq = lane >> 4;
    #pragma unroll
    for (int ni = 0; ni < 4; ++ni) {
        int n = bn0 + wn*64 + ni*16 + fr;
        float bn_ = bias[n];
        int g = n >> 11, rem = n & 2047;
        int h_ = rem >> 8, w_ = rem & 255;
        #pragma unroll
        for (int mi = 0; mi < 4; ++mi) {
            int m0 = bm0 + wm*64 + mi*16 + fq*4;
            int b_ = m0 >> 9, t0 = m0 & 511;
            float v0 = acc[mi][ni][0] + bn_;
            float v1 = acc[mi][ni][1] + bn_;
            float v2 = acc[mi][ni][2] + bn_;
            float v3 = acc[mi][ni][3] + bn_;
            if (g == 0) {   // q as f16 [bh][t][w] for k2
                ushort* dq = q + ((size_t)(b_*H + h_)*T + t0)*D + w_;
                dq[0] = f2h(v0); dq[D] = f2h(v1); dq[2*D] = f2h(v2); dq[3*D] = f2h(v3);
            } else {        // vf/vb bf16 transposed [bh][w][t] for k4
                ushort* dv = (g == 1 ? vf : vb) + ((size_t)(b_*H + h_)*D + w_)*T + t0;
                *(ushort4*)dv = make_ushort4(f2b(v0), f2b(v1), f2b(v2), f2b(v3));
            }
        }
    }
}

// ---- K2a: Qsum[bh][s] = sum_w q_f16 ; Ksum[bh][d] = sum_w f16(xh*wkh) ------
// Must use the SAME f16 values as k2's inner loop (identity consistency).
__global__ __launch_bounds__(256) void k2a_sums(const ushort* __restrict__ qh,
        const ushort* __restrict__ xh, const uint* __restrict__ wkh,
        float* __restrict__ Qsum, float* __restrict__ Ksum) {
    int row = blockIdx.x * 4 + (threadIdx.x >> 6);   // 0..32767
    int lane = threadIdx.x & 63;
    float s;
    if (row < BH*T) {
        uint2 u = *(const uint2*)&qh[(size_t)row*D + lane*4];
        f16x2 a = __builtin_bit_cast(f16x2, u.x);
        f16x2 b = __builtin_bit_cast(f16x2, u.y);
        s = (float)a[0] + (float)a[1] + (float)b[0] + (float)b[1];
    } else {
        int idx = row - BH*T;            // = bh*512 + d
        int b_ = idx >> 12;
        int h_ = (idx >> 9) & 7;
        int d_ = idx & 511;
        uint2 xu = *(const uint2*)&xh[((size_t)(b_*T + d_))*D + lane*4];
        uint2 wv = *(const uint2*)&wkh[h_*128 + lane*2];
        f16x2 p0 = __builtin_bit_cast(f16x2, xu.x) * __builtin_bit_cast(f16x2, wv.x);
        f16x2 p1 = __builtin_bit_cast(f16x2, xu.y) * __builtin_bit_cast(f16x2, wv.y);
        s = (float)p0[0] + (float)p0[1] + (float)p1[0] + (float)p1[1];
    }
    #pragma unroll
    for (int o = 32; o > 0; o >>= 1) s += __shfl_xor(s, o);
    if (lane == 0) {
        if (row < BH*T) Qsum[row] = s; else Ksum[row - BH*T] = s;
    }
}

// ---- K2: E = exp(-SCALE*(2*sum max(q,k) - Qsum - Ksum)), E + E^T out -------
// 128x128 block tile, 8x8 per thread, 2-inst packed-f16 inner (max+add).
__global__ __launch_bounds__(256) void k2_scores(const ushort* __restrict__ qh,
        const ushort* __restrict__ xh, const uint* __restrict__ wkh,
        const float* __restrict__ Qsum, const float* __restrict__ Ksum,
        ushort* __restrict__ E, ushort* __restrict__ Et) {
    __shared__ uint Qs[32*132];    // [w-pair up][s 0..127], stride 132
    __shared__ uint KsA[32*68];    // [up][d 0..63], stride 68
    __shared__ uint KsB[32*68];    // [up][d 64..127]
    int s0 = blockIdx.x * 128, d0 = blockIdx.y * 128, bh = blockIdx.z;
    int b_ = bh >> 3, h_ = bh & 7;
    int tid = threadIdx.x;
    int tx = tid & 15, ty = tid >> 4;
    const ushort* qbase = qh + (size_t)bh * T * D;
    const ushort* xbase = xh + (size_t)b_ * T * D;
    int srow = tid >> 3;           // 0..31
    int c = (tid & 7) * 8;         // w-offset within 64-chunk
    int c2 = c >> 1;               // up-base
    float accf[8][8] = {};
    for (int w0 = 0; w0 < D; w0 += 64) {
        // ---- stage Q: coalesced uint4 copies, pairs along w ----
        #pragma unroll
        for (int p = 0; p < 4; ++p) {
            int r = srow + p*32;
            uint4 u = *(const uint4*)&qbase[(size_t)(s0+r)*D + w0 + c];
            Qs[(c2+0)*132 + r] = u.x;
            Qs[(c2+1)*132 + r] = u.y;
            Qs[(c2+2)*132 + r] = u.z;
            Qs[(c2+3)*132 + r] = u.w;
        }
        // ---- stage K: k = f16(x*wk) pairs ----
        uint4 wv = *(const uint4*)&wkh[h_*128 + (w0>>1) + c2];
        #pragma unroll
        for (int p = 0; p < 4; ++p) {
            int r = srow + p*32;
            uint4 xv = *(const uint4*)&xbase[(size_t)(d0+r)*D + w0 + c];
            uint k0 = __builtin_bit_cast(uint, __builtin_bit_cast(f16x2, xv.x) * __builtin_bit_cast(f16x2, wv.x));
            uint k1 = __builtin_bit_cast(uint, __builtin_bit_cast(f16x2, xv.y) * __builtin_bit_cast(f16x2, wv.y));
            uint k2_ = __builtin_bit_cast(uint, __builtin_bit_cast(f16x2, xv.z) * __builtin_bit_cast(f16x2, wv.z));
            uint k3_ = __builtin_bit_cast(uint, __builtin_bit_cast(f16x2, xv.w) * __builtin_bit_cast(f16x2, wv.w));
            uint* dst = (p < 2) ? KsA : KsB;
            int rr = srow + (p & 1)*32;
            dst[(c2+0)*68 + rr] = k0;
            dst[(c2+1)*68 + rr] = k1;
            dst[(c2+2)*68 + rr] = k2_;
            dst[(c2+3)*68 + rr] = k3_;
        }
        __syncthreads();
        // ---- inner: 32 pair-steps, 64 (i,j) 2-inst max+add ----
        uint acc2[8][8];
        #pragma unroll
        for (int i = 0; i < 8; ++i)
            #pragma unroll
            for (int j = 0; j < 8; ++j) acc2[i][j] = 0u;
        #pragma unroll 2
        for (int up = 0; up < 32; ++up) {
            u32x4 qA = *(const u32x4*)&Qs[up*132 + ty*8];
            u32x4 qB = *(const u32x4*)&Qs[up*132 + ty*8 + 4];
            u32x4 kA = *(const u32x4*)&KsA[up*68 + tx*4];
            u32x4 kB = *(const u32x4*)&KsB[up*68 + tx*4];
            uint q8[8] = {qA.x, qA.y, qA.z, qA.w, qB.x, qB.y, qB.z, qB.w};
            uint k8[8] = {kA.x, kA.y, kA.z, kA.w, kB.x, kB.y, kB.z, kB.w};
            #pragma unroll
            for (int i = 0; i < 8; ++i) {
                #pragma unroll
                for (int j = 0; j < 8; ++j) {
                    uint t;
                    asm("v_pk_max_f16 %1, %2, %3\n\t"
                        "v_pk_add_f16 %0, %0, %1"
                        : "+v"(acc2[i][j]), "=&v"(t)
                        : "v"(q8[i]), "v"(k8[j]));
                }
            }
        }
        // fold f16 partials (64 w-terms) into f32
        #pragma unroll
        for (int i = 0; i < 8; ++i)
            #pragma unroll
            for (int j = 0; j < 8; ++j) {
                f16x2 t = __builtin_bit_cast(f16x2, acc2[i][j]);
                accf[i][j] += (float)t[0] + (float)t[1];
            }
        __syncthreads();
    }
    // ---- epilogue: a = -SCALE*(2*M - Qsum - Ksum); e = exp(a) ----
    float qs8[8], ks8[8];
    {
        float4 qlo = *(const float4*)&Qsum[bh*T + s0 + ty*8];
        float4 qhi = *(const float4*)&Qsum[bh*T + s0 + ty*8 + 4];
        qs8[0]=qlo.x; qs8[1]=qlo.y; qs8[2]=qlo.z; qs8[3]=qlo.w;
        qs8[4]=qhi.x; qs8[5]=qhi.y; qs8[6]=qhi.z; qs8[7]=qhi.w;
        float4 klo = *(const float4*)&Ksum[bh*T + d0 + tx*4];
        float4 khi = *(const float4*)&Ksum[bh*T + d0 + 64 + tx*4];
        ks8[0]=klo.x; ks8[1]=klo.y; ks8[2]=klo.z; ks8[3]=klo.w;
        ks8[4]=khi.x; ks8[5]=khi.y; ks8[6]=khi.z; ks8[7]=khi.w;
    }
    #pragma unroll
    for (int i = 0; i < 8; ++i)
        #pragma unroll
        for (int j = 0; j < 8; ++j)
            accf[i][j] = __expf(-SCALE * (2.f*accf[i][j] - qs8[i] - ks8[j]));
    #pragma unroll
    for (int i = 0; i < 8; ++i) {
        int s = s0 + ty*8 + i;
        *(ushort4*)&E[((size_t)bh*T + s)*T + d0 + tx*4] =
            make_ushort4(f2b(accf[i][0]), f2b(accf[i][1]), f2b(accf[i][2]), f2b(accf[i][3]));
        *(ushort4*)&E[((size_t)bh*T + s)*T + d0 + 64 + tx*4] =
            make_ushort4(f2b(accf[i][4]), f2b(accf[i][5]), f2b(accf[i][6]), f2b(accf[i][7]));
    }
    #pragma unroll
    for (int j = 0; j < 8; ++j) {
        int d = d0 + (j < 4 ? tx*4 + j : 64 + tx*4 + (j-4));
        ushort* dst = &Et[((size_t)bh*T + d)*T + s0 + ty*8];
        *(ushort4*)dst = make_ushort4(f2b(accf[0][j]), f2b(accf[1][j]), f2b(accf[2][j]), f2b(accf[3][j]));
        *(ushort4*)(dst+4) = make_ushort4(f2b(accf[4][j]), f2b(accf[5][j]), f2b(accf[6][j]), f2b(accf[7][j]));
    }
}

// ---- K3: rsum[bh][s] = sum_d E ; csum[bh][d] = sum_s E (rows of Et) --------
__global__ __launch_bounds__(256) void k3_sums(const ushort* __restrict__ E,
        const ushort* __restrict__ Et, float* __restrict__ rsum, float* __restrict__ csum) {
    int row = blockIdx.x * 4 + (threadIdx.x >> 6);
    int lane = threadIdx.x & 63;
    const ushort* src; float* dst;
    if (row < BH*T) { src = E + (size_t)row*T; dst = rsum + row; }
    else            { src = Et + (size_t)(row - BH*T)*T; dst = csum + (row - BH*T); }
    uint4 u = *(const uint4*)&src[lane*8];
    const ushort* up = (const ushort*)&u;
    float s = 0.f;
    #pragma unroll
    for (int j = 0; j < 8; ++j) s += b2f(up[j]);
    #pragma unroll
    for (int o = 32; o > 0; o >>= 1) s += __shfl_xor(s, o);
    if (lane == 0) *dst = s;
}

// ---- K4: dual bf16 MFMA GEMM: part[bh][d][w] = (Et.Vf)/csum[d] + (E.Vb)/rsum[d]
__global__ __launch_bounds__(256) void k4_attn(const ushort* __restrict__ E,
        const ushort* __restrict__ Et, const ushort* __restrict__ vfT,
        const ushort* __restrict__ vbT, const float* __restrict__ rsum,
        const float* __restrict__ csum, float* __restrict__ part) {
    __shared__ ushort A1[128*40];
    __shared__ ushort A2[128*40];
    __shared__ ushort Bf[64*40];
    __shared__ ushort Bb[64*40];
    int d0 = blockIdx.x * 128, w0 = blockIdx.y * 64, bh = blockIdx.z;
    const ushort* Ebb = E  + (size_t)bh*T*T;
    const ushort* Etb = Et + (size_t)bh*T*T;
    const ushort* vfb = vfT + (size_t)bh*D*T;
    const ushort* vbb = vbT + (size_t)bh*D*T;
    int tid = threadIdx.x, lane = tid & 63, wave = tid >> 6;
    int wm = wave >> 1, wn = wave & 1;
    int sr = tid >> 2, sc = (tid & 3) * 8;
    int fr = lane & 15, fg = (lane >> 4) * 8;
    f32x4 acc1[4][2] = {}, acc2[4][2] = {};
    for (int s0 = 0; s0 < T; s0 += 32) {
        *(uint4*)&A1[sr*40 + sc]      = *(const uint4*)&Etb[(size_t)(d0+sr)*T + s0 + sc];
        *(uint4*)&A1[(sr+64)*40 + sc] = *(const uint4*)&Etb[(size_t)(d0+sr+64)*T + s0 + sc];
        *(uint4*)&A2[sr*40 + sc]      = *(const uint4*)&Ebb[(size_t)(d0+sr)*T + s0 + sc];
        *(uint4*)&A2[(sr+64)*40 + sc] = *(const uint4*)&Ebb[(size_t)(d0+sr+64)*T + s0 + sc];
        *(uint4*)&Bf[sr*40 + sc]      = *(const uint4*)&vfb[(size_t)(w0+sr)*T + s0 + sc];
        *(uint4*)&Bb[sr*40 + sc]      = *(const uint4*)&vbb[(size_t)(w0+sr)*T + s0 + sc];
        __syncthreads();
        bf16x8 a1[4], a2[4], bfv[2], bbv[2];
        #pragma unroll
        for (int i = 0; i < 4; ++i) {
            a1[i] = *(const bf16x8*)&A1[(wm*64 + i*16 + fr)*40 + fg];
            a2[i] = *(const bf16x8*)&A2[(wm*64 + i*16 + fr)*40 + fg];
        }
        #pragma unroll
        for (int i = 0; i < 2; ++i) {
            bfv[i] = *(const bf16x8*)&Bf[(wn*32 + i*16 + fr)*40 + fg];
            bbv[i] = *(const bf16x8*)&Bb[(wn*32 + i*16 + fr)*40 + fg];
        }
        #pragma unroll
        for (int mi = 0; mi < 4; ++mi)
            #pragma unroll
            for (int ni = 0; ni < 2; ++ni) {
                acc1[mi][ni] = __builtin_amdgcn_mfma_f32_16x16x32_bf16(a1[mi], bfv[ni], acc1[mi][ni], 0, 0, 0);
                acc2[mi][ni] = __builtin_amdgcn_mfma_f32_16x16x32_bf16(a2[mi], bbv[ni], acc2[mi][ni], 0, 0, 0);
            }
        __syncthreads();
    }
    int fq = lane >> 4;
    float* pb = part + (size_t)bh*T*D;
    #pragma unroll
    for (int mi = 0; mi < 4; ++mi)
        #pragma unroll
        for (int r = 0; r < 4; ++r) {
            int d = d0 + wm*64 + mi*16 + fq*4 + r;
            float ic = 1.f / csum[bh*T + d];
            float ir = 1.f / rsum[bh*T + d];
            #pragma unroll
            for (int ni = 0; ni < 2; ++ni) {
                int w = w0 + wn*32 + ni*16 + fr;
                pb[(size_t)d*D + w] = acc1[mi][ni][r]*ic + acc2[mi][ni][r]*ir;
            }
        }
}

// ---- K4b: head-reduce + SiLU ----------------------------------------------
__global__ __launch_bounds__(256) void k4b_reduce_silu(const float* __restrict__ part,
        float* __restrict__ z) {
    int idx = blockIdx.x * 256 + threadIdx.x;
    int b_ = idx >> 17;
    int td = idx & 131071;
    float s = 0.f;
    #pragma unroll
    for (int h = 0; h < H; ++h)
        s += part[(size_t)(b_*H + h) * T * D + td];
    z[idx] = s / (1.f + __expf(-1.702f * s));
}

// ---- K5: out = x + z @ fanin_w^T + fanin_b (fp32, small) -------------------
__global__ __launch_bounds__(256) void k5_fanin(const float* __restrict__ z,
        const float* __restrict__ fw, const float* __restrict__ fb,
        const float* __restrict__ x, float* __restrict__ out) {
    __shared__ float As[64][33];
    __shared__ float Bs[32][68];
    int bm = blockIdx.x * 64;
    int bn = blockIdx.y * 64;
    int tid = threadIdx.x;
    int tx = tid & 15, ty = tid >> 4;
    float acc[4][4] = {};
    for (int k0 = 0; k0 < 256; k0 += 32) {
        int r = tid >> 3, c4 = (tid & 7) * 4;
        for (int rr = r; rr < 64; rr += 32) {
            float4 v = *(const float4*)&z[(size_t)(bm + rr) * 256 + k0 + c4];
            As[rr][c4+0]=v.x; As[rr][c4+1]=v.y; As[rr][c4+2]=v.z; As[rr][c4+3]=v.w;
        }
        for (int nn = r; nn < 64; nn += 32) {
            float4 v = *(const float4*)&fw[(size_t)(bn + nn) * 256 + k0 + c4];
            Bs[c4+0][nn]=v.x; Bs[c4+1][nn]=v.y; Bs[c4+2][nn]=v.z; Bs[c4+3][nn]=v.w;
        }
        __syncthreads();
        for (int kk = 0; kk < 32; ++kk) {
            float a[4];
            #pragma unroll
            for (int i=0;i<4;++i) a[i] = As[ty*4+i][kk];
            float4 bv = *(const float4*)&Bs[kk][tx*4];
            #pragma unroll
            for (int i=0;i<4;++i) {
                acc[i][0] += a[i]*bv.x; acc[i][1] += a[i]*bv.y;
                acc[i][2] += a[i]*bv.z; acc[i][3] += a[i]*bv.w;
            }
        }
        __syncthreads();
    }
    #pragma unroll
    for (int i=0;i<4;++i) {
        int m = bm + ty*4 + i;
        int n = bn + tx*4;
        float4 xv = *(const float4*)&x[(size_t)m*256 + n];
        float4 v;
        v.x = acc[i][0] + fb[n+0] + xv.x;
        v.y = acc[i][1] + fb[n+1] + xv.y;
        v.z = acc[i][2] + fb[n+2] + xv.z;
        v.w = acc[i][3] + fb[n+3] + xv.w;
        *(float4*)&out[(size_t)m*256 + n] = v;
    }
}

extern "C" void kernel_launch(void* const* d_in, const int* in_sizes, int n_in,
                              void* d_out, int out_size, void* d_ws, size_t ws_size,
                              hipStream_t stream) {
    const float* x       = (const float*)d_in[0];
    const float* wk      = (const float*)d_in[1];
    const float* wqv_w   = (const float*)d_in[2];
    const float* wqv_b   = (const float*)d_in[3];
    const float* fanin_w = (const float*)d_in[4];
    const float* fanin_b = (const float*)d_in[5];
    char* wsb = (char*)d_ws;
    ushort* xb   = (ushort*)(wsb);                 // 1,048,576 B (bf16 x)
    ushort* wqvb = (ushort*)(wsb + 1048576);       // 3,145,728  (bf16 wqv)
    ushort* qb   = (ushort*)(wsb + 4194304);       // 8,388,608  q f16 [bh][t][w]
    ushort* vfT  = (ushort*)(wsb + 12582912);      // 8,388,608  bf16 [bh][w][t]
    ushort* vbT  = (ushort*)(wsb + 20971520);      // 8,388,608
    ushort* Eb   = (ushort*)(wsb + 29360128);      // 16,777,216 bf16 [bh][s][d]
    ushort* Etb  = (ushort*)(wsb + 46137344);      // 16,777,216 bf16 [bh][d][s]
    float*  rsum = (float*)(wsb + 62914560);       // 65,536
    float*  csum = (float*)(wsb + 62980096);       // 65,536
    float*  part = (float*)(wsb + 63045632);       // 16,777,216 (written by k4)
    // live only k0..k2, overlapped inside the (later-written) part region:
    ushort* xh   = (ushort*)(wsb + 63045632);      // 1,048,576  f16 x
    ushort* wkh  = (ushort*)(wsb + 64094208);      // 4,096      f16 wk
    float*  Qsum = (float*)(wsb + 64098304);       // 65,536
    float*  Ksum = (float*)(wsb + 64163840);       // 65,536
    float*  z    = (float*)(wsb + 79822848);       // 2,097,152
    float* out   = (float*)d_out;

    k0_convert     <<<2050, 256, 0, stream>>>(x, wqv_w, wk, xb, xh, wqvb, (ushort*)wkh);
    k1_qkv         <<<dim3(16, 48), 256, 0, stream>>>(xb, wqvb, wqv_b, qb, vfT, vbT);
    k2a_sums       <<<8192, 256, 0, stream>>>(qb, xh, (const uint*)wkh, Qsum, Ksum);
    k2_scores      <<<dim3(4, 4, 32), 256, 0, stream>>>(qb, xh, (const uint*)wkh, Qsum, Ksum, Eb, Etb);
    k3_sums        <<<8192, 256, 0, stream>>>(Eb, Etb, rsum, csum);
    k4_attn        <<<dim3(4, 4, 32), 256, 0, stream>>>(Eb, Etb, vfT, vbT, rsum, csum, part);
    k4b_reduce_silu<<<2048, 256, 0, stream>>>(part, z);
    k5_fanin       <<<dim3(32, 4), 256, 0, stream>>>(z, fanin_w, fanin_b, x, out);
}

// Round 6
// 236.723 us; speedup vs baseline: 2.8910x; 1.0077x over previous
//
#include <hip/hip_runtime.h>
#include <hip/hip_bf16.h>
#include <math.h>

#define B 4
#define T 512
#define D 256
#define H 8
#define BH (B*H)
#define SCALE 0.0625f

typedef float f32x4 __attribute__((ext_vector_type(4)));
typedef short bf16x8 __attribute__((ext_vector_type(8)));
typedef _Float16 f16x2 __attribute__((ext_vector_type(2)));

__device__ __forceinline__ ushort f2b(float f) {
    __hip_bfloat16 h = __float2bfloat16(f);
    return *reinterpret_cast<ushort*>(&h);
}
__device__ __forceinline__ float b2f(ushort u) {
    __hip_bfloat16 h;
    *reinterpret_cast<ushort*>(&h) = u;
    return __bfloat162float(h);
}
__device__ __forceinline__ ushort f2h(float f) {
    _Float16 h = (_Float16)f;
    ushort u; __builtin_memcpy(&u, &h, 2); return u;
}
// single-instruction packed-f16 ops (asm: avoids bf16-header overload clash,
// one inst per block so the scheduler can interleave independent chains)
__device__ __forceinline__ uint hmax2u(uint a, uint b) {
    uint d; asm("v_pk_max_f16 %0, %1, %2" : "=v"(d) : "v"(a), "v"(b)); return d;
}
__device__ __forceinline__ uint hadd2u(uint a, uint b) {
    uint d; asm("v_pk_add_f16 %0, %1, %2" : "=v"(d) : "v"(a), "v"(b)); return d;
}
__device__ __forceinline__ uint hmul2u(uint a, uint b) {
    uint d; asm("v_pk_mul_f16 %0, %1, %2" : "=v"(d) : "v"(a), "v"(b)); return d;
}
__device__ __forceinline__ float h2lo(uint u) {
    f16x2 t = __builtin_bit_cast(f16x2, u); return (float)t[0];
}
__device__ __forceinline__ float h2hi(uint u) {
    f16x2 t = __builtin_bit_cast(f16x2, u); return (float)t[1];
}

// ---- K0: x -> bf16 (k1) + f16 (k2); wqv_w -> bf16; wk -> f16 ---------------
__global__ __launch_bounds__(256) void k0_convert(const float* __restrict__ x,
        const float* __restrict__ w, const float* __restrict__ wk,
        ushort* __restrict__ xb, ushort* __restrict__ xh,
        ushort* __restrict__ wb, ushort* __restrict__ wkh) {
    int i = blockIdx.x * 256 + threadIdx.x;
    if (i < 131072) {
        float4 v = ((const float4*)x)[i];
        ((ushort4*)xb)[i] = make_ushort4(f2b(v.x), f2b(v.y), f2b(v.z), f2b(v.w));
        ((ushort4*)xh)[i] = make_ushort4(f2h(v.x), f2h(v.y), f2h(v.z), f2h(v.w));
    } else if (i < 524288) {
        int j = i - 131072;
        float4 v = ((const float4*)w)[j];
        ((ushort4*)wb)[j] = make_ushort4(f2b(v.x), f2b(v.y), f2b(v.z), f2b(v.w));
    } else if (i < 524288 + 512) {
        int j = i - 524288;
        float4 v = ((const float4*)wk)[j];
        ((ushort4*)wkh)[j] = make_ushort4(f2h(v.x), f2h(v.y), f2h(v.z), f2h(v.w));
    }
}

// ---- K1: bf16 MFMA GEMM  v = x @ wqv^T + bias ------------------------------
// q(f16) [bh][t][w] direct; vf/vb(bf16) [bh][w][t] via LDS transpose epilogue.
__global__ __launch_bounds__(256) void k1_qkv(const ushort* __restrict__ xb,
        const ushort* __restrict__ wb, const float* __restrict__ bias,
        ushort* __restrict__ q, ushort* __restrict__ vf, ushort* __restrict__ vb) {
    __shared__ ushort AB[2*128*40];
    ushort* As = AB;
    ushort* Bs = AB + 128*40;
    int tid = threadIdx.x;
    int lane = tid & 63, wave = tid >> 6;
    int wm = wave >> 1, wn = wave & 1;
    int bm0 = blockIdx.x * 128, bn0 = blockIdx.y * 128;
    f32x4 acc[4][4] = {};
    int sr = tid >> 2, sc = (tid & 3) * 8;
    int fr = lane & 15, fg = (lane >> 4) * 8;
    for (int k0 = 0; k0 < 256; k0 += 32) {
        *(uint4*)&As[sr*40 + sc]      = *(const uint4*)&xb[(size_t)(bm0+sr)*256 + k0 + sc];
        *(uint4*)&As[(sr+64)*40 + sc] = *(const uint4*)&xb[(size_t)(bm0+sr+64)*256 + k0 + sc];
        *(uint4*)&Bs[sr*40 + sc]      = *(const uint4*)&wb[(size_t)(bn0+sr)*256 + k0 + sc];
        *(uint4*)&Bs[(sr+64)*40 + sc] = *(const uint4*)&wb[(size_t)(bn0+sr+64)*256 + k0 + sc];
        __syncthreads();
        bf16x8 af[4], bfv[4];
        #pragma unroll
        for (int i = 0; i < 4; ++i)
            af[i] = *(const bf16x8*)&As[(wm*64 + i*16 + fr)*40 + fg];
        #pragma unroll
        for (int i = 0; i < 4; ++i)
            bfv[i] = *(const bf16x8*)&Bs[(wn*64 + i*16 + fr)*40 + fg];
        #pragma unroll
        for (int mi = 0; mi < 4; ++mi)
            #pragma unroll
            for (int ni = 0; ni < 4; ++ni)
                acc[mi][ni] = __builtin_amdgcn_mfma_f32_16x16x32_bf16(af[mi], bfv[ni], acc[mi][ni], 0, 0, 0);
        __syncthreads();
    }
    int fq = lane >> 4;
    int g = bn0 >> 11;
    if (g == 0) {
        // q path: f16, [bh][t][w]
        #pragma unroll
        for (int ni = 0; ni < 4; ++ni) {
            int n = bn0 + wn*64 + ni*16 + fr;
            float bn_ = bias[n];
            int h_ = (n & 2047) >> 8, w_ = n & 255;
            #pragma unroll
            for (int mi = 0; mi < 4; ++mi) {
                int m0 = bm0 + wm*64 + mi*16 + fq*4;
                int b_ = m0 >> 9, t0 = m0 & 511;
                ushort* dq = q + ((size_t)(b_*H + h_)*T + t0)*D + w_;
                dq[0]   = f2h(acc[mi][ni][0] + bn_);
                dq[D]   = f2h(acc[mi][ni][1] + bn_);
                dq[2*D] = f2h(acc[mi][ni][2] + bn_);
                dq[3*D] = f2h(acc[mi][ni][3] + bn_);
            }
        }
    } else {
        // vf/vb path: bf16, transposed [bh][w][t] via LDS (coalesced stores)
        ushort* dstbase = (g == 1) ? vf : vb;
        int b_ = bm0 >> 9;
        int t0base = bm0 & 511;
        ushort* tb = AB;               // 128 n x 68 (m-half 64 + pad)
        #pragma unroll
        for (int hf = 0; hf < 2; ++hf) {
            __syncthreads();
            if (wm == hf) {
                #pragma unroll
                for (int ni = 0; ni < 4; ++ni) {
                    int nloc = wn*64 + ni*16 + fr;
                    float bn_ = bias[bn0 + nloc];
                    #pragma unroll
                    for (int mi = 0; mi < 4; ++mi) {
                        int mloc = mi*16 + fq*4;
                        *(ushort4*)&tb[nloc*68 + mloc] = make_ushort4(
                            f2b(acc[mi][ni][0] + bn_), f2b(acc[mi][ni][1] + bn_),
                            f2b(acc[mi][ni][2] + bn_), f2b(acc[mi][ni][3] + bn_));
                    }
                }
            }
            __syncthreads();
            #pragma unroll
            for (int p = 0; p < 2; ++p) {
                int rr = (tid >> 2) + p*64;       // n_local
                int cc = (tid & 3) * 16;          // m within half
                const ushort* src = &tb[rr*68 + cc];
                uint2 a0 = *(const uint2*)(src);
                uint2 a1 = *(const uint2*)(src + 4);
                uint2 a2 = *(const uint2*)(src + 8);
                uint2 a3 = *(const uint2*)(src + 12);
                int n = bn0 + rr;
                int h_ = (n & 2047) >> 8, w_ = n & 255;
                ushort* dst = dstbase + ((size_t)(b_*H + h_)*D + w_)*T + t0base + hf*64 + cc;
                *(uint4*)dst       = make_uint4(a0.x, a0.y, a1.x, a1.y);
                *(uint4*)(dst + 8) = make_uint4(a2.x, a2.y, a3.x, a3.y);
            }
        }
    }
}

// ---- K2a: Qsum/Ksum (same f16 values as k2 inner) + zero rsum/csum ---------
__global__ __launch_bounds__(256) void k2a_sums(const ushort* __restrict__ qh,
        const ushort* __restrict__ xh, const uint* __restrict__ wkh,
        float* __restrict__ Qsum, float* __restrict__ Ksum,
        float* __restrict__ zerobase) {
    if (blockIdx.x < 32) {
        int zi = blockIdx.x * 256 + threadIdx.x;   // 8192 float4 = rsum+csum
        ((float4*)zerobase)[zi] = make_float4(0.f, 0.f, 0.f, 0.f);
    }
    int row = blockIdx.x * 4 + (threadIdx.x >> 6);   // 0..32767
    int lane = threadIdx.x & 63;
    float s;
    if (row < BH*T) {
        uint2 u = *(const uint2*)&qh[(size_t)row*D + lane*4];
        s = h2lo(u.x) + h2hi(u.x) + h2lo(u.y) + h2hi(u.y);
    } else {
        int idx = row - BH*T;
        int b_ = idx >> 12;
        int h_ = (idx >> 9) & 7;
        int d_ = idx & 511;
        uint2 xu = *(const uint2*)&xh[((size_t)(b_*T + d_))*D + lane*4];
        uint2 wv = *(const uint2*)&wkh[h_*128 + lane*2];
        uint p0 = hmul2u(xu.x, wv.x);
        uint p1 = hmul2u(xu.y, wv.y);
        s = h2lo(p0) + h2hi(p0) + h2lo(p1) + h2hi(p1);
    }
    #pragma unroll
    for (int o = 32; o > 0; o >>= 1) s += __shfl_xor(s, o);
    if (lane == 0) {
        if (row < BH*T) Qsum[row] = s; else Ksum[row - BH*T] = s;
    }
}

// ---- K2: E = exp(-SCALE*(2*sum max(q,k) - Qsum - Ksum)); E, Et, rsum, csum -
// 128s x 64d tile, grid (4,8,32)=1024 blocks. Stride-130 LDS (2-way free).
__global__ __launch_bounds__(256) void k2_scores(const ushort* __restrict__ qh,
        const ushort* __restrict__ xh, const uint* __restrict__ wkh,
        const float* __restrict__ Qsum, const float* __restrict__ Ksum,
        ushort* __restrict__ E, ushort* __restrict__ Et,
        float* __restrict__ rsum, float* __restrict__ csum) {
    __shared__ uint SM[8320];
    __shared__ float cspart[64];
    uint* Qs = SM;            // [32 up][128 s] stride 130
    uint* Ks = SM + 4160;     // [32 up][64 d]  stride 130
    int s0 = blockIdx.x * 128, d0 = blockIdx.y * 64, bh = blockIdx.z;
    int b_ = bh >> 3, h_ = bh & 7;
    int tid = threadIdx.x;
    int tx = tid & 15, ty = tid >> 4;
    const ushort* qbase = qh + (size_t)bh * T * D;
    const ushort* xbase = xh + (size_t)b_ * T * D;
    if (tid < 64) cspart[tid] = 0.f;
    int r4 = tid >> 2;
    int cb = (tid & 3) * 16;
    int up0 = cb >> 1;
    float accf[8][4] = {};
    for (int w0 = 0; w0 < D; w0 += 64) {
        // ---- stage Q (128 rows x 64 w) ----
        #pragma unroll
        for (int p = 0; p < 2; ++p) {
            int r = r4 + p*64;
            const ushort* src = &qbase[(size_t)(s0+r)*D + w0 + cb];
            uint4 u0 = *(const uint4*)src;
            uint4 u1 = *(const uint4*)(src + 8);
            Qs[(up0+0)*130 + r] = u0.x; Qs[(up0+1)*130 + r] = u0.y;
            Qs[(up0+2)*130 + r] = u0.z; Qs[(up0+3)*130 + r] = u0.w;
            Qs[(up0+4)*130 + r] = u1.x; Qs[(up0+5)*130 + r] = u1.y;
            Qs[(up0+6)*130 + r] = u1.z; Qs[(up0+7)*130 + r] = u1.w;
        }
        // ---- stage K (64 rows x 64 w), k = f16(x*wk) ----
        {
            const ushort* src = &xbase[(size_t)(d0+r4)*D + w0 + cb];
            uint4 x0 = *(const uint4*)src;
            uint4 x1 = *(const uint4*)(src + 8);
            const uint* wp = &wkh[h_*128 + ((w0 + cb) >> 1)];
            uint4 w0v = *(const uint4*)wp;
            uint4 w1v = *(const uint4*)(wp + 4);
            Ks[(up0+0)*130 + r4] = hmul2u(x0.x, w0v.x);
            Ks[(up0+1)*130 + r4] = hmul2u(x0.y, w0v.y);
            Ks[(up0+2)*130 + r4] = hmul2u(x0.z, w0v.z);
            Ks[(up0+3)*130 + r4] = hmul2u(x0.w, w0v.w);
            Ks[(up0+4)*130 + r4] = hmul2u(x1.x, w1v.x);
            Ks[(up0+5)*130 + r4] = hmul2u(x1.y, w1v.y);
            Ks[(up0+6)*130 + r4] = hmul2u(x1.z, w1v.z);
            Ks[(up0+7)*130 + r4] = hmul2u(x1.w, w1v.w);
        }
        __syncthreads();
        uint acc2[8][4];
        #pragma unroll
        for (int i = 0; i < 8; ++i)
            #pragma unroll
            for (int j = 0; j < 4; ++j) acc2[i][j] = 0u;
        #pragma unroll 2
        for (int up = 0; up < 32; ++up) {
            const uint* qrow = &Qs[up*130 + ty*8];
            uint2 qa = *(const uint2*)qrow;
            uint2 qb2 = *(const uint2*)(qrow + 2);
            uint2 qc = *(const uint2*)(qrow + 4);
            uint2 qd = *(const uint2*)(qrow + 6);
            const uint* krow = &Ks[up*130 + tx*4];
            uint2 ka = *(const uint2*)krow;
            uint2 kb = *(const uint2*)(krow + 2);
            uint q8[8] = {qa.x, qa.y, qb2.x, qb2.y, qc.x, qc.y, qd.x, qd.y};
            uint k4v[4] = {ka.x, ka.y, kb.x, kb.y};
            #pragma unroll
            for (int i = 0; i < 8; ++i)
                #pragma unroll
                for (int j = 0; j < 4; ++j)
                    acc2[i][j] = hadd2u(acc2[i][j], hmax2u(q8[i], k4v[j]));
        }
        #pragma unroll
        for (int i = 0; i < 8; ++i)
            #pragma unroll
            for (int j = 0; j < 4; ++j)
                accf[i][j] += h2lo(acc2[i][j]) + h2hi(acc2[i][j]);
        __syncthreads();
    }
    // ---- epilogue: e = exp(-SCALE*(2M - Qsum - Ksum)) ----
    float qs8[8], ks4[4];
    {
        float4 qlo = *(const float4*)&Qsum[bh*T + s0 + ty*8];
        float4 qhi = *(const float4*)&Qsum[bh*T + s0 + ty*8 + 4];
        qs8[0]=qlo.x; qs8[1]=qlo.y; qs8[2]=qlo.z; qs8[3]=qlo.w;
        qs8[4]=qhi.x; qs8[5]=qhi.y; qs8[6]=qhi.z; qs8[7]=qhi.w;
        float4 kv = *(const float4*)&Ksum[bh*T + d0 + tx*4];
        ks4[0]=kv.x; ks4[1]=kv.y; ks4[2]=kv.z; ks4[3]=kv.w;
    }
    #pragma unroll
    for (int i = 0; i < 8; ++i)
        #pragma unroll
        for (int j = 0; j < 4; ++j)
            accf[i][j] = __expf(-SCALE * (2.f*accf[i][j] - qs8[i] - ks4[j]));
    // E stores (row-major, coalesced)
    #pragma unroll
    for (int i = 0; i < 8; ++i)
        *(ushort4*)&E[((size_t)bh*T + s0 + ty*8 + i)*T + d0 + tx*4] =
            make_ushort4(f2b(accf[i][0]), f2b(accf[i][1]), f2b(accf[i][2]), f2b(accf[i][3]));
    // rsum: reduce over tx (16-lane groups) + atomic
    #pragma unroll
    for (int i = 0; i < 8; ++i) {
        float rs = accf[i][0] + accf[i][1] + accf[i][2] + accf[i][3];
        rs += __shfl_xor(rs, 1); rs += __shfl_xor(rs, 2);
        rs += __shfl_xor(rs, 4); rs += __shfl_xor(rs, 8);
        if ((tid & 15) == 0) atomicAdd(&rsum[bh*T + s0 + ty*8 + i], rs);
    }
    // csum partials into LDS
    #pragma unroll
    for (int j = 0; j < 4; ++j) {
        float cs = 0.f;
        #pragma unroll
        for (int i = 0; i < 8; ++i) cs += accf[i][j];
        atomicAdd(&cspart[tx*4 + j], cs);
    }
    __syncthreads();
    // Et via LDS transpose (tb aliases SM), stride 132
    ushort* tb = (ushort*)SM;
    #pragma unroll
    for (int j = 0; j < 4; ++j) {
        int drow = tx*4 + j;
        *(ushort4*)&tb[drow*132 + ty*8] = make_ushort4(
            f2b(accf[0][j]), f2b(accf[1][j]), f2b(accf[2][j]), f2b(accf[3][j]));
        *(ushort4*)&tb[drow*132 + ty*8 + 4] = make_ushort4(
            f2b(accf[4][j]), f2b(accf[5][j]), f2b(accf[6][j]), f2b(accf[7][j]));
    }
    if (tid < 64) atomicAdd(&csum[bh*T + d0 + tid], cspart[tid]);
    __syncthreads();
    #pragma unroll
    for (int p = 0; p < 2; ++p) {
        int rr = (tid >> 3) + p*32;       // d_local
        int sc = (tid & 7) * 16;          // s offset
        const ushort* src = &tb[rr*132 + sc];
        uint2 a0 = *(const uint2*)(src);
        uint2 a1 = *(const uint2*)(src + 4);
        uint2 a2 = *(const uint2*)(src + 8);
        uint2 a3 = *(const uint2*)(src + 12);
        ushort* dst = &Et[((size_t)bh*T + d0 + rr)*T + s0 + sc];
        *(uint4*)dst       = make_uint4(a0.x, a0.y, a1.x, a1.y);
        *(uint4*)(dst + 8) = make_uint4(a2.x, a2.y, a3.x, a3.y);
    }
}

// ---- K4: dual bf16 MFMA GEMM: part[bh][d][w] = (Et.Vf)/csum[d] + (E.Vb)/rsum[d]
__global__ __launch_bounds__(256) void k4_attn(const ushort* __restrict__ E,
        const ushort* __restrict__ Et, const ushort* __restrict__ vfT,
        const ushort* __restrict__ vbT, const float* __restrict__ rsum,
        const float* __restrict__ csum, float* __restrict__ part) {
    __shared__ ushort A1[128*40];
    __shared__ ushort A2[128*40];
    __shared__ ushort Bf[64*40];
    __shared__ ushort Bb[64*40];
    int d0 = blockIdx.x * 128, w0 = blockIdx.y * 64, bh = blockIdx.z;
    const ushort* Ebb = E  + (size_t)bh*T*T;
    const ushort* Etb = Et + (size_t)bh*T*T;
    const ushort* vfb = vfT + (size_t)bh*D*T;
    const ushort* vbb = vbT + (size_t)bh*D*T;
    int tid = threadIdx.x, lane = tid & 63, wave = tid >> 6;
    int wm = wave >> 1, wn = wave & 1;
    int sr = tid >> 2, sc = (tid & 3) * 8;
    int fr = lane & 15, fg = (lane >> 4) * 8;
    f32x4 acc1[4][2] = {}, acc2[4][2] = {};
    for (int s0 = 0; s0 < T; s0 += 32) {
        *(uint4*)&A1[sr*40 + sc]      = *(const uint4*)&Etb[(size_t)(d0+sr)*T + s0 + sc];
        *(uint4*)&A1[(sr+64)*40 + sc] = *(const uint4*)&Etb[(size_t)(d0+sr+64)*T + s0 + sc];
        *(uint4*)&A2[sr*40 + sc]      = *(const uint4*)&Ebb[(size_t)(d0+sr)*T + s0 + sc];
        *(uint4*)&A2[(sr+64)*40 + sc] = *(const uint4*)&Ebb[(size_t)(d0+sr+64)*T + s0 + sc];
        *(uint4*)&Bf[sr*40 + sc]      = *(const uint4*)&vfb[(size_t)(w0+sr)*T + s0 + sc];
        *(uint4*)&Bb[sr*40 + sc]      = *(const uint4*)&vbb[(size_t)(w0+sr)*T + s0 + sc];
        __syncthreads();
        bf16x8 a1[4], a2[4], bfv[2], bbv[2];
        #pragma unroll
        for (int i = 0; i < 4; ++i) {
            a1[i] = *(const bf16x8*)&A1[(wm*64 + i*16 + fr)*40 + fg];
            a2[i] = *(const bf16x8*)&A2[(wm*64 + i*16 + fr)*40 + fg];
        }
        #pragma unroll
        for (int i = 0; i < 2; ++i) {
            bfv[i] = *(const bf16x8*)&Bf[(wn*32 + i*16 + fr)*40 + fg];
            bbv[i] = *(const bf16x8*)&Bb[(wn*32 + i*16 + fr)*40 + fg];
        }
        #pragma unroll
        for (int mi = 0; mi < 4; ++mi)
            #pragma unroll
            for (int ni = 0; ni < 2; ++ni) {
                acc1[mi][ni] = __builtin_amdgcn_mfma_f32_16x16x32_bf16(a1[mi], bfv[ni], acc1[mi][ni], 0, 0, 0);
                acc2[mi][ni] = __builtin_amdgcn_mfma_f32_16x16x32_bf16(a2[mi], bbv[ni], acc2[mi][ni], 0, 0, 0);
            }
        __syncthreads();
    }
    int fq = lane >> 4;
    float* pb = part + (size_t)bh*T*D;
    #pragma unroll
    for (int mi = 0; mi < 4; ++mi)
        #pragma unroll
        for (int r = 0; r < 4; ++r) {
            int d = d0 + wm*64 + mi*16 + fq*4 + r;
            float ic = 1.f / csum[bh*T + d];
            float ir = 1.f / rsum[bh*T + d];
            #pragma unroll
            for (int ni = 0; ni < 2; ++ni) {
                int w = w0 + wn*32 + ni*16 + fr;
                pb[(size_t)d*D + w] = acc1[mi][ni][r]*ic + acc2[mi][ni][r]*ir;
            }
        }
}

// ---- K4b: head-reduce + SiLU ----------------------------------------------
__global__ __launch_bounds__(256) void k4b_reduce_silu(const float* __restrict__ part,
        float* __restrict__ z) {
    int idx = blockIdx.x * 256 + threadIdx.x;
    int b_ = idx >> 17;
    int td = idx & 131071;
    float s = 0.f;
    #pragma unroll
    for (int h = 0; h < H; ++h)
        s += part[(size_t)(b_*H + h) * T * D + td];
    z[idx] = s / (1.f + __expf(-1.702f * s));
}

// ---- K5: out = x + z @ fanin_w^T + fanin_b (fp32, small) -------------------
__global__ __launch_bounds__(256) void k5_fanin(const float* __restrict__ z,
        const float* __restrict__ fw, const float* __restrict__ fb,
        const float* __restrict__ x, float* __restrict__ out) {
    __shared__ float As[64][33];
    __shared__ float Bs[32][68];
    int bm = blockIdx.x * 64;
    int bn = blockIdx.y * 64;
    int tid = threadIdx.x;
    int tx = tid & 15, ty = tid >> 4;
    float acc[4][4] = {};
    for (int k0 = 0; k0 < 256; k0 += 32) {
        int r = tid >> 3, c4 = (tid & 7) * 4;
        for (int rr = r; rr < 64; rr += 32) {
            float4 v = *(const float4*)&z[(size_t)(bm + rr) * 256 + k0 + c4];
            As[rr][c4+0]=v.x; As[rr][c4+1]=v.y; As[rr][c4+2]=v.z; As[rr][c4+3]=v.w;
        }
        for (int nn = r; nn < 64; nn += 32) {
            float4 v = *(const float4*)&fw[(size_t)(bn + nn) * 256 + k0 + c4];
            Bs[c4+0][nn]=v.x; Bs[c4+1][nn]=v.y; Bs[c4+2][nn]=v.z; Bs[c4+3][nn]=v.w;
        }
        __syncthreads();
        for (int kk = 0; kk < 32; ++kk) {
            float a[4];
            #pragma unroll
            for (int i=0;i<4;++i) a[i] = As[ty*4+i][kk];
            float4 bv = *(const float4*)&Bs[kk][tx*4];
            #pragma unroll
            for (int i=0;i<4;++i) {
                acc[i][0] += a[i]*bv.x; acc[i][1] += a[i]*bv.y;
                acc[i][2] += a[i]*bv.z; acc[i][3] += a[i]*bv.w;
            }
        }
        __syncthreads();
    }
    #pragma unroll
    for (int i=0;i<4;++i) {
        int m = bm + ty*4 + i;
        int n = bn + tx*4;
        float4 xv = *(const float4*)&x[(size_t)m*256 + n];
        float4 v;
        v.x = acc[i][0] + fb[n+0] + xv.x;
        v.y = acc[i][1] + fb[n+1] + xv.y;
        v.z = acc[i][2] + fb[n+2] + xv.z;
        v.w = acc[i][3] + fb[n+3] + xv.w;
        *(float4*)&out[(size_t)m*256 + n] = v;
    }
}

extern "C" void kernel_launch(void* const* d_in, const int* in_sizes, int n_in,
                              void* d_out, int out_size, void* d_ws, size_t ws_size,
                              hipStream_t stream) {
    const float* x       = (const float*)d_in[0];
    const float* wk      = (const float*)d_in[1];
    const float* wqv_w   = (const float*)d_in[2];
    const float* wqv_b   = (const float*)d_in[3];
    const float* fanin_w = (const float*)d_in[4];
    const float* fanin_b = (const float*)d_in[5];
    char* wsb = (char*)d_ws;
    ushort* xb   = (ushort*)(wsb);                 // 1,048,576 B (bf16 x)
    ushort* wqvb = (ushort*)(wsb + 1048576);       // 3,145,728  (bf16 wqv)
    ushort* qb   = (ushort*)(wsb + 4194304);       // 8,388,608  q f16 [bh][t][w]
    ushort* vfT  = (ushort*)(wsb + 12582912);      // 8,388,608  bf16 [bh][w][t]
    ushort* vbT  = (ushort*)(wsb + 20971520);      // 8,388,608
    ushort* Eb   = (ushort*)(wsb + 29360128);      // 16,777,216 bf16 [bh][s][d]
    ushort* Etb  = (ushort*)(wsb + 46137344);      // 16,777,216 bf16 [bh][d][s]
    float*  rsum = (float*)(wsb + 62914560);       // 65,536  (adjacent to csum)
    float*  csum = (float*)(wsb + 62980096);       // 65,536
    float*  part = (float*)(wsb + 63045632);       // 16,777,216 (written by k4)
    // live only k0..k2, overlapped inside the (later-written) part region:
    ushort* xh   = (ushort*)(wsb + 63045632);      // 1,048,576  f16 x
    ushort* wkh  = (ushort*)(wsb + 64094208);      // 4,096      f16 wk
    float*  Qsum = (float*)(wsb + 64098304);       // 65,536
    float*  Ksum = (float*)(wsb + 64163840);       // 65,536
    float*  z    = (float*)(wsb + 79822848);       // 2,097,152
    float* out   = (float*)d_out;

    k0_convert     <<<2050, 256, 0, stream>>>(x, wqv_w, wk, xb, xh, wqvb, (ushort*)wkh);
    k1_qkv         <<<dim3(16, 48), 256, 0, stream>>>(xb, wqvb, wqv_b, qb, vfT, vbT);
    k2a_sums       <<<8192, 256, 0, stream>>>(qb, xh, (const uint*)wkh, Qsum, Ksum, rsum);
    k2_scores      <<<dim3(4, 8, 32), 256, 0, stream>>>(qb, xh, (const uint*)wkh, Qsum, Ksum, Eb, Etb, rsum, csum);
    k4_attn        <<<dim3(4, 4, 32), 256, 0, stream>>>(Eb, Etb, vfT, vbT, rsum, csum, part);
    k4b_reduce_silu<<<2048, 256, 0, stream>>>(part, z);
    k5_fanin       <<<dim3(32, 4), 256, 0, stream>>>(z, fanin_w, fanin_b, x, out);
}